// Round 3
// baseline (3538.829 us; speedup 1.0000x reference)
//
#include <hip/hip_runtime.h>

#define NN 100000
#define EE 320000

typedef unsigned int uint32;

__device__ __forceinline__ float4 ld4(const float* p){ return *(const float4*)p; }
__device__ __forceinline__ void st4(float* p, const float4 v){ *(float4*)p = v; }
__device__ __forceinline__ float sigm(float x){ return 1.f/(1.f + expf(-x)); }

constexpr int AM_DENSE=0, AM_EFEAT=1;
constexpr int EM_STORE=0, EM_BRELU=1, EM_BNLK=2, EM_SCAT=3;

// ---------------------------------------------------------------------------
// Generic tiled GEMM: 64 rows/block, all NOUT cols, BK=16, 256 threads,
// micro-tile 4 rows x (NOUT/16) cols per thread.
// ---------------------------------------------------------------------------
template<int K,int NOUT,int AM,int EM>
__global__ __launch_bounds__(256) void gemm_k(
    const float* __restrict__ A,
    const int* __restrict__ eidx,
    const float* __restrict__ W, const float* __restrict__ bias,
    const float* __restrict__ bng,
    float* __restrict__ C, float* __restrict__ C2, int M)
{
  constexpr int CN = NOUT/16;
  __shared__ float As[16][68];        // [k][row], +4 pad
  __shared__ float Ws[16][NOUT];      // [k][col]
  __shared__ int sidx[64], didx[64];
  const int t  = threadIdx.x;
  const int tx = t & 15, ty = t >> 4;
  const int row0 = blockIdx.x * 64;

  if constexpr (AM != AM_DENSE) {
    if (t < 64) {
      int e = row0 + t; int s=0,d=0;
      if (e < M){ s = eidx[2*e]; d = eidx[2*e+1]; }
      sidx[t]=s; didx[t]=d;
    }
    __syncthreads();
  }

  float acc[4][CN];
  #pragma unroll
  for (int i=0;i<4;i++)
    #pragma unroll
    for (int j=0;j<CN;j++) acc[i][j]=0.f;

  const int r_st  = t >> 2;        // 0..63 : row within tile
  const int kq_st = (t & 3) * 4;   // 0,4,8,12 : k offset within BK

  for (int k0=0;k0<K;k0+=16) {
    // ---- stage A (64 x 16, transposed into LDS) ----
    {
      float4 v = make_float4(0.f,0.f,0.f,0.f);
      const int gr = row0 + r_st;
      const int kk = k0 + kq_st;
      if (gr < M) {
        if constexpr (AM == AM_DENSE) {
          v = ld4(A + (size_t)gr*K + kk);
        } else { // AM_EFEAT: concat(nf[s], nf[d]-nf[s])
          const int s=sidx[r_st], d=didx[r_st];
          if (kk < 128) v = ld4(A + (size_t)s*128 + kk);
          else {
            float4 a = ld4(A + (size_t)d*128 + (kk-128));
            float4 b = ld4(A + (size_t)s*128 + (kk-128));
            v.x=a.x-b.x; v.y=a.y-b.y; v.z=a.z-b.z; v.w=a.w-b.w;
          }
        }
      }
      As[kq_st+0][r_st]=v.x; As[kq_st+1][r_st]=v.y;
      As[kq_st+2][r_st]=v.z; As[kq_st+3][r_st]=v.w;
    }
    // ---- stage W (16 x NOUT) ----
    {
      constexpr int C4 = NOUT/4;
      for (int i=t;i<16*C4;i+=256){ int kk=i/C4, c4=(i%C4)*4;
        st4(&Ws[kk][c4], ld4(W + (size_t)(k0+kk)*NOUT + c4)); }
    }
    __syncthreads();
    // ---- compute ----
    #pragma unroll
    for (int kk=0;kk<16;kk++){
      float a0,a1,a2,a3;
      { const float4 av = *(const float4*)&As[kk][ty*4]; a0=av.x;a1=av.y;a2=av.z;a3=av.w; }
      float b[CN];
      if constexpr ((CN & 3) == 0) {
        #pragma unroll
        for (int j4=0;j4<CN;j4+=4){
          const float4 bv = *(const float4*)&Ws[kk][tx*CN+j4];
          b[j4]=bv.x;b[j4+1]=bv.y;b[j4+2]=bv.z;b[j4+3]=bv.w; }
      } else {
        #pragma unroll
        for (int j=0;j<CN;j++) b[j]=Ws[kk][tx*CN+j];
      }
      #pragma unroll
      for (int j=0;j<CN;j++){
        acc[0][j]=fmaf(a0,b[j],acc[0][j]);
        acc[1][j]=fmaf(a1,b[j],acc[1][j]);
        acc[2][j]=fmaf(a2,b[j],acc[2][j]);
        acc[3][j]=fmaf(a3,b[j],acc[3][j]);
      }
    }
    __syncthreads();
  }

  // ---- epilogue ----
  float sc[CN], sh[CN];
  if constexpr (EM==EM_BNLK) {
    const float r_ = rsqrtf(1.f + 1e-5f);
    #pragma unroll
    for (int j=0;j<CN;j++){ int c=tx*CN+j; sc[j]=bng[c]*r_; sh[j]=bias[c]; }
  }
  #pragma unroll
  for (int i=0;i<4;i++){
    const int rr = ty*4+i;
    const int r  = row0 + rr;
    if (r >= M) continue;
    #pragma unroll
    for (int j=0;j<CN;j++){
      const int c = tx*CN+j;
      float v = acc[i][j];
      if constexpr (EM==EM_BRELU) v = fmaxf(v + bias[c], 0.f);
      else if constexpr (EM==EM_BNLK){ float x = fmaf(v, sc[j], sh[j]); v = (x>0.f)? x : 0.2f*x; }
      if constexpr (EM==EM_SCAT){
        v += bias[c];
        atomicAdd(&C [(size_t)sidx[rr]*NOUT + c], v);
        atomicAdd(&C2[(size_t)didx[rr]*NOUT + c], v);
      } else {
        C[(size_t)r*NOUT + c] = v;
      }
    }
  }
}

// ---------------------------------------------------------------------------
// Fused: G = sigmoid(concat(ni[s],ni[d]) @ nredW + nredb)   (kept in LDS)
//        ef1 = relu(concat(nf[s], nf[d]-nf[s]) @ emlp1W + emlp1b) * G
// ---------------------------------------------------------------------------
__global__ __launch_bounds__(256) void k_ani_ef1(
  const float* __restrict__ nf, const float* __restrict__ ni,
  const int* __restrict__ eidx,
  const float* __restrict__ Wn, const float* __restrict__ bn_,
  const float* __restrict__ W1, const float* __restrict__ b1,
  float* __restrict__ ef1)
{
  __shared__ float As[16][68];
  __shared__ float Ws[16][128];
  __shared__ float G[64][132];
  __shared__ int sidx[64], didx[64];
  const int t=threadIdx.x, tx=t&15, ty=t>>4;
  const int row0 = blockIdx.x*64;
  if (t<64){ sidx[t]=eidx[2*(row0+t)]; didx[t]=eidx[2*(row0+t)+1]; }
  __syncthreads();
  const int r_st=t>>2, kq=(t&3)*4;

  float acc[4][8];
  // ---------------- pass 1: node-indicator gate ----------------
  #pragma unroll
  for (int i=0;i<4;i++)
    #pragma unroll
    for (int j=0;j<8;j++) acc[i][j]=0.f;
  for (int k0=0;k0<256;k0+=16){
    {
      const int kk=k0+kq, s=sidx[r_st], d=didx[r_st];
      float4 v = (kk<128)? ld4(ni+(size_t)s*128+kk) : ld4(ni+(size_t)d*128+(kk-128));
      As[kq+0][r_st]=v.x; As[kq+1][r_st]=v.y; As[kq+2][r_st]=v.z; As[kq+3][r_st]=v.w;
    }
    for (int i=t;i<16*32;i+=256){ int k2=i>>5, c4=(i&31)*4;
      st4(&Ws[k2][c4], ld4(Wn+(size_t)(k0+k2)*128+c4)); }
    __syncthreads();
    #pragma unroll
    for (int kk=0;kk<16;kk++){
      float a0,a1,a2,a3;
      { const float4 av=*(const float4*)&As[kk][ty*4]; a0=av.x;a1=av.y;a2=av.z;a3=av.w; }
      float b[8];
      #pragma unroll
      for (int j4=0;j4<8;j4+=4){ const float4 bv=*(const float4*)&Ws[kk][tx*8+j4];
        b[j4]=bv.x;b[j4+1]=bv.y;b[j4+2]=bv.z;b[j4+3]=bv.w; }
      #pragma unroll
      for (int j=0;j<8;j++){
        acc[0][j]=fmaf(a0,b[j],acc[0][j]); acc[1][j]=fmaf(a1,b[j],acc[1][j]);
        acc[2][j]=fmaf(a2,b[j],acc[2][j]); acc[3][j]=fmaf(a3,b[j],acc[3][j]);
      }
    }
    __syncthreads();
  }
  #pragma unroll
  for (int i=0;i<4;i++)
    #pragma unroll
    for (int j=0;j<8;j++){
      const int c=tx*8+j;
      G[ty*4+i][c] = sigm(acc[i][j] + bn_[c]);
    }
  __syncthreads();

  // ---------------- pass 2: edge-feature MLP1, gated ----------------
  #pragma unroll
  for (int i=0;i<4;i++)
    #pragma unroll
    for (int j=0;j<8;j++) acc[i][j]=0.f;
  for (int k0=0;k0<256;k0+=16){
    {
      const int kk=k0+kq, s=sidx[r_st], d=didx[r_st];
      float4 v;
      if (kk<128) v = ld4(nf+(size_t)s*128+kk);
      else {
        float4 a=ld4(nf+(size_t)d*128+(kk-128)), b=ld4(nf+(size_t)s*128+(kk-128));
        v.x=a.x-b.x; v.y=a.y-b.y; v.z=a.z-b.z; v.w=a.w-b.w;
      }
      As[kq+0][r_st]=v.x; As[kq+1][r_st]=v.y; As[kq+2][r_st]=v.z; As[kq+3][r_st]=v.w;
    }
    for (int i=t;i<16*32;i+=256){ int k2=i>>5, c4=(i&31)*4;
      st4(&Ws[k2][c4], ld4(W1+(size_t)(k0+k2)*128+c4)); }
    __syncthreads();
    #pragma unroll
    for (int kk=0;kk<16;kk++){
      float a0,a1,a2,a3;
      { const float4 av=*(const float4*)&As[kk][ty*4]; a0=av.x;a1=av.y;a2=av.z;a3=av.w; }
      float b[8];
      #pragma unroll
      for (int j4=0;j4<8;j4+=4){ const float4 bv=*(const float4*)&Ws[kk][tx*8+j4];
        b[j4]=bv.x;b[j4+1]=bv.y;b[j4+2]=bv.z;b[j4+3]=bv.w; }
      #pragma unroll
      for (int j=0;j<8;j++){
        acc[0][j]=fmaf(a0,b[j],acc[0][j]); acc[1][j]=fmaf(a1,b[j],acc[1][j]);
        acc[2][j]=fmaf(a2,b[j],acc[2][j]); acc[3][j]=fmaf(a3,b[j],acc[3][j]);
      }
    }
    __syncthreads();
  }
  #pragma unroll
  for (int i=0;i<4;i++){
    const int r = row0 + ty*4+i;
    #pragma unroll
    for (int j=0;j<8;j++){
      const int c=tx*8+j;
      float v = fmaxf(acc[i][j] + b1[c], 0.f) * G[ty*4+i][c];
      ef1[(size_t)r*128 + c] = v;
    }
  }
}

// ---------------------------------------------------------------------------
// Fused edge head: ef1 -> ef2=relu(@W2+b2) [regs] -> ex=leakyBN(@W3) [regs]
//                  -> elog = ex @ W4 (128->27), written directly to d_out.
// ef2/ex are streamed column-chunk-wise through the As buffer.
// ---------------------------------------------------------------------------
__global__ __launch_bounds__(256) void k_ehead(
  const float* __restrict__ ef1,
  const float* __restrict__ W2, const float* __restrict__ b2,
  const float* __restrict__ W3, const float* __restrict__ g3, const float* __restrict__ b3,
  const float* __restrict__ W4,
  float* __restrict__ elog)
{
  __shared__ float As[16][68];
  __shared__ float Ws[16][256];
  const int t=threadIdx.x, tx=t&15, ty=t>>4;
  const int row0 = blockIdx.x*64;
  const int r_st=t>>2, kq=(t&3)*4;

  // ---- pass 3: ef2 = relu(ef1 @ W2 + b2), 64x256 tile in regs
  float acc3[4][16];
  #pragma unroll
  for (int i=0;i<4;i++)
    #pragma unroll
    for (int j=0;j<16;j++) acc3[i][j]=0.f;
  for (int k0=0;k0<128;k0+=16){
    {
      const float4 v = ld4(ef1 + (size_t)(row0+r_st)*128 + k0+kq);
      As[kq+0][r_st]=v.x; As[kq+1][r_st]=v.y; As[kq+2][r_st]=v.z; As[kq+3][r_st]=v.w;
    }
    for (int i=t;i<16*64;i+=256){ int k2=i>>6, c4=(i&63)*4;
      st4(&Ws[k2][c4], ld4(W2+(size_t)(k0+k2)*256+c4)); }
    __syncthreads();
    #pragma unroll
    for (int kk=0;kk<16;kk++){
      float a0,a1,a2,a3;
      { const float4 av=*(const float4*)&As[kk][ty*4]; a0=av.x;a1=av.y;a2=av.z;a3=av.w; }
      float b[16];
      #pragma unroll
      for (int j4=0;j4<16;j4+=4){ const float4 bv=*(const float4*)&Ws[kk][tx*16+j4];
        b[j4]=bv.x;b[j4+1]=bv.y;b[j4+2]=bv.z;b[j4+3]=bv.w; }
      #pragma unroll
      for (int j=0;j<16;j++){
        acc3[0][j]=fmaf(a0,b[j],acc3[0][j]); acc3[1][j]=fmaf(a1,b[j],acc3[1][j]);
        acc3[2][j]=fmaf(a2,b[j],acc3[2][j]); acc3[3][j]=fmaf(a3,b[j],acc3[3][j]);
      }
    }
    __syncthreads();
  }
  #pragma unroll
  for (int i=0;i<4;i++)
    #pragma unroll
    for (int j=0;j<16;j++)
      acc3[i][j] = fmaxf(acc3[i][j] + b2[tx*16+j], 0.f);

  // ---- pass 4: acc4 = ef2 @ W3 (256->128); ef2 streamed 16 cols at a time
  float acc4[4][8];
  #pragma unroll
  for (int i=0;i<4;i++)
    #pragma unroll
    for (int j=0;j<8;j++) acc4[i][j]=0.f;
  for (int kc=0;kc<16;kc++){
    if (tx==kc){
      #pragma unroll
      for (int i=0;i<4;i++)
        #pragma unroll
        for (int j=0;j<16;j++) As[j][ty*4+i] = acc3[i][j];
    }
    for (int i=t;i<16*32;i+=256){ int k2=i>>5, c4=(i&31)*4;
      st4(&Ws[k2][c4], ld4(W3+(size_t)(kc*16+k2)*128+c4)); }
    __syncthreads();
    #pragma unroll
    for (int kk=0;kk<16;kk++){
      float a0,a1,a2,a3;
      { const float4 av=*(const float4*)&As[kk][ty*4]; a0=av.x;a1=av.y;a2=av.z;a3=av.w; }
      float b[8];
      #pragma unroll
      for (int j4=0;j4<8;j4+=4){ const float4 bv=*(const float4*)&Ws[kk][tx*8+j4];
        b[j4]=bv.x;b[j4+1]=bv.y;b[j4+2]=bv.z;b[j4+3]=bv.w; }
      #pragma unroll
      for (int j=0;j<8;j++){
        acc4[0][j]=fmaf(a0,b[j],acc4[0][j]); acc4[1][j]=fmaf(a1,b[j],acc4[1][j]);
        acc4[2][j]=fmaf(a2,b[j],acc4[2][j]); acc4[3][j]=fmaf(a3,b[j],acc4[3][j]);
      }
    }
    __syncthreads();
  }
  {
    const float r_ = rsqrtf(1.f+1e-5f);
    #pragma unroll
    for (int j=0;j<8;j++){
      const int c=tx*8+j;
      const float sc=g3[c]*r_, sh=b3[c];
      #pragma unroll
      for (int i=0;i<4;i++){
        float x = fmaf(acc4[i][j], sc, sh);
        acc4[i][j] = (x>0.f)? x : 0.2f*x;
      }
    }
  }

  // ---- pass 5: elog = ex @ W4 (128->27); ex streamed 8 cols at a time
  float acc5[4][2];
  #pragma unroll
  for (int i=0;i<4;i++){ acc5[i][0]=0.f; acc5[i][1]=0.f; }
  for (int kc=0;kc<16;kc++){
    if (tx==kc){
      #pragma unroll
      for (int i=0;i<4;i++)
        #pragma unroll
        for (int j=0;j<8;j++) As[j][ty*4+i] = acc4[i][j];
    }
    { int kk=t>>5, c=t&31;
      Ws[kk][c] = (c<27)? W4[(size_t)(kc*8+kk)*27+c] : 0.f; }
    __syncthreads();
    #pragma unroll
    for (int kk=0;kk<8;kk++){
      float a0,a1,a2,a3;
      { const float4 av=*(const float4*)&As[kk][ty*4]; a0=av.x;a1=av.y;a2=av.z;a3=av.w; }
      const float b0=Ws[kk][tx*2], b1=Ws[kk][tx*2+1];
      acc5[0][0]=fmaf(a0,b0,acc5[0][0]); acc5[0][1]=fmaf(a0,b1,acc5[0][1]);
      acc5[1][0]=fmaf(a1,b0,acc5[1][0]); acc5[1][1]=fmaf(a1,b1,acc5[1][1]);
      acc5[2][0]=fmaf(a2,b0,acc5[2][0]); acc5[2][1]=fmaf(a2,b1,acc5[2][1]);
      acc5[3][0]=fmaf(a3,b0,acc5[3][0]); acc5[3][1]=fmaf(a3,b1,acc5[3][1]);
    }
    __syncthreads();
  }
  #pragma unroll
  for (int i=0;i<4;i++){
    const int r = row0 + ty*4+i;
    #pragma unroll
    for (int j=0;j<2;j++){
      const int c = tx*2+j;
      if (c<27) elog[(size_t)r*27+c] = acc5[i][j];
    }
  }
}

// ---------------------------- small kernels --------------------------------
__global__ void k_count(const int* __restrict__ eidx, float* a, float* b, int E){
  int e = blockIdx.x*256+threadIdx.x; if (e>=E) return;
  atomicAdd(&a[eidx[2*e]],   1.f);
  atomicAdd(&b[eidx[2*e+1]], 1.f);
}
__global__ void k_dis(const float* __restrict__ cd, float* __restrict__ dis, int n){
  int i=blockIdx.x*256+threadIdx.x; if(i>=n)return;
  dis[i]=rsqrtf(cd[i]+1.f);
}
// aei may alias rs (element-wise in-place)
__global__ void k_aei(const float* __restrict__ rs, const float* __restrict__ cs,
                      const float* __restrict__ cns, const float* __restrict__ cnd,
                      float* __restrict__ aei, int n){
  int idx=blockIdx.x*256+threadIdx.x; if(idx>=n*16)return;
  int i=idx>>4, q=(idx&15)*4;
  float ir=1.f/fmaxf(cns[i],1.f), ic=1.f/fmaxf(cnd[i],1.f);
  float4 a=ld4(rs+(size_t)i*64+q), b=ld4(cs+(size_t)i*64+q);
  float4 o;
  o.x=sigm(a.x*ir*(b.x*ic)); o.y=sigm(a.y*ir*(b.y*ic));
  o.z=sigm(a.z*ir*(b.z*ic)); o.w=sigm(a.w*ir*(b.w*ic));
  st4(aei+(size_t)i*64+q, o);
}
// h may alias agg (element-wise in-place)
template<int NC, bool AEI>
__global__ void k_hcomb(const float* __restrict__ agg, const float* __restrict__ lin,
                        const float* __restrict__ aei, const float* __restrict__ dis,
                        const float* __restrict__ bias, float* __restrict__ h, int n){
  constexpr int Q = NC/4;
  int idx=blockIdx.x*256+threadIdx.x; if(idx>=n*Q)return;
  int i=idx/Q, q=(idx%Q)*4;
  float d2=dis[i]; d2*=d2;
  float4 ag=ld4(agg+(size_t)i*NC+q), ln=ld4(lin+(size_t)i*NC+q), b=ld4(bias+q);
  float4 o;
  o.x=fmaxf(fmaf(ln.x,d2,ag.x)+b.x,0.f); o.y=fmaxf(fmaf(ln.y,d2,ag.y)+b.y,0.f);
  o.z=fmaxf(fmaf(ln.z,d2,ag.z)+b.z,0.f); o.w=fmaxf(fmaf(ln.w,d2,ag.w)+b.w,0.f);
  if (AEI){ float4 m=ld4(aei+(size_t)i*NC+q); o.x*=m.x;o.y*=m.y;o.z*=m.z;o.w*=m.w; }
  st4(h+(size_t)i*NC+q,o);
}
template<int NC>
__global__ void k_scatter(const float* __restrict__ lin, float* __restrict__ agg,
                          const int* __restrict__ eidx, const float* __restrict__ dis, int E){
  constexpr int Q=NC/4;
  int idx=blockIdx.x*256+threadIdx.x; if (idx>=E*Q) return;
  int e=idx/Q, q=(idx%Q)*4;
  int s=eidx[2*e], d=eidx[2*e+1];
  float w=dis[s]*dis[d];
  float4 v=ld4(lin+(size_t)s*NC+q);
  float* p=agg+(size_t)d*NC+q;
  atomicAdd(p+0,v.x*w); atomicAdd(p+1,v.y*w); atomicAdd(p+2,v.z*w); atomicAdd(p+3,v.w*w);
}
__global__ __launch_bounds__(256) void k_softmax_row(float* __restrict__ x, int M){
  const int wave = threadIdx.x>>6, lane = threadIdx.x&63;
  const int r = blockIdx.x*4 + wave; if (r>=M) return;
  float* p = x + (size_t)r*160;
  float v0 = p[lane], v1 = p[64+lane];
  float v2 = (lane<32)? p[128+lane] : -3.4e38f;
  float m = fmaxf(fmaxf(v0,v1),v2);
  for (int o=32;o;o>>=1) m = fmaxf(m, __shfl_xor(m,o));
  float e0=expf(v0-m), e1=expf(v1-m), e2=(lane<32)?expf(v2-m):0.f;
  float s=e0+e1+e2;
  for (int o=32;o;o>>=1) s += __shfl_xor(s,o);
  float inv = 1.f/s;
  p[lane]=e0*inv; p[64+lane]=e1*inv; if(lane<32)p[128+lane]=e2*inv;
}
__global__ void k_colmax(const float* __restrict__ x, uint32* __restrict__ cmax_u, int E){
  __shared__ float red[8][32];
  const int t=threadIdx.x, col=t&31, seg=t>>5;
  float m = -3.4e38f;
  if (col < 27)
    for (int r = blockIdx.x*8 + seg; r < E; r += gridDim.x*8)
      m = fmaxf(m, x[(size_t)r*27+col]);
  red[seg][col]=m; __syncthreads();
  if (t<32){
    float mm=red[0][t];
    #pragma unroll
    for (int s2=1;s2<8;s2++) mm=fmaxf(mm,red[s2][t]);
    if (t<27){
      uint32 u=__float_as_uint(mm);
      u = (u&0x80000000u)? ~u : (u|0x80000000u);
      atomicMax(&cmax_u[t], u);
    }
  }
}
__global__ void k_colfix(const uint32* __restrict__ cmax_u, float* __restrict__ cmaxf){
  int t=threadIdx.x; if (t>=27) return;
  uint32 u=cmax_u[t];
  cmaxf[t] = (u&0x80000000u)? __uint_as_float(u&0x7FFFFFFFu) : __uint_as_float(~u);
}
__global__ void k_colsum(const float* __restrict__ x, const float* __restrict__ cmaxf,
                         float* __restrict__ csum, int E){
  __shared__ float red[8][32];
  const int t=threadIdx.x, col=t&31, seg=t>>5;
  float s = 0.f;
  if (col < 27){
    const float cm = cmaxf[col];
    for (int r = blockIdx.x*8 + seg; r < E; r += gridDim.x*8)
      s += expf(x[(size_t)r*27+col] - cm);
  }
  red[seg][col]=s; __syncthreads();
  if (t<32){
    float ss=red[0][t];
    #pragma unroll
    for (int s2=1;s2<8;s2++) ss+=red[s2][t];
    if (t<27) atomicAdd(&csum[t], ss);
  }
}
__global__ void k_colnorm(float* __restrict__ x, const float* __restrict__ cmaxf,
                          const float* __restrict__ csum, int E){
  int idx=blockIdx.x*256+threadIdx.x;
  if (idx >= E*27) return;
  int c = idx - (idx/27)*27;
  x[idx] = expf(x[idx]-cmaxf[c]) / csum[c];
}

// ---------------------------------------------------------------------------
extern "C" void kernel_launch(void* const* d_in, const int* in_sizes, int n_in,
                              void* d_out, int out_size, void* d_ws, size_t ws_size,
                              hipStream_t stream)
{
  const float* nf     = (const float*)d_in[0];
  const int*   eidx   = (const int*)  d_in[1];
  const float* gcn1W  = (const float*)d_in[2];
  const float* gcn1b  = (const float*)d_in[3];
  const float* gcn2W  = (const float*)d_in[4];
  const float* gcn2b  = (const float*)d_in[5];
  const float* eattnW = (const float*)d_in[6];
  const float* eattnb = (const float*)d_in[7];
  const float* nattnW = (const float*)d_in[8];
  const float* nattnb = (const float*)d_in[9];
  const float* nredW  = (const float*)d_in[10];
  const float* nredb  = (const float*)d_in[11];
  const float* emlp1W = (const float*)d_in[12];
  const float* emlp1b = (const float*)d_in[13];
  const float* emlp2W = (const float*)d_in[14];
  const float* emlp2b = (const float*)d_in[15];
  const float* nlin1W = (const float*)d_in[16];
  const float* nbng   = (const float*)d_in[17];
  const float* nbnb   = (const float*)d_in[18];
  const float* nlin2W = (const float*)d_in[19];
  const float* elin1W = (const float*)d_in[20];
  const float* ebng   = (const float*)d_in[21];
  const float* ebnb   = (const float*)d_in[22];
  const float* elin2W = (const float*)d_in[23];
  (void)in_sizes; (void)n_in; (void)out_size; (void)ws_size;

  const size_t N = NN, E = EE;
  float* out  = (float*)d_out;
  float* nlog = out;               // N*160
  float* elog = out + N*160;       // E*27

  // ---- workspace plan: peak = N*256 + E*128 + 96 floats ~= 266 MB ----
  float* ws   = (float*)d_ws;
  float* agg2 = ws;                   // [0, N*128)  agg2 -> h2 (in place)
  float* h2   = agg2;
  float* lin2 = ws + N*128;           // [N*128, N*256)  lin2 -> niB -> nx
  float* niB  = lin2;
  float* nx   = lin2;
  float* ef1  = ws + N*256;           // [N*256, N*256+E*128)
  // early buffers live INSIDE the ef1 span (all dead before ef1 is written):
  float* rs   = ef1;                  // N*64 ; -> aei in place
  float* aei  = rs;
  float* cs   = ws + N*320;           // N*64
  float* lin1 = ws + N*384;           // N*64
  float* agg1 = ws + N*448;           // N*64 ; -> h1 in place
  float* h1   = agg1;
  float* cnts = ws + N*512;           // N
  float* cntd = cnts + N;             // N
  float* dis  = cnts + 2*N;           // N
  float* smalls = ws + N*256 + E*128; // 96 floats above ef1

  // 1. degrees
  (void)hipMemsetAsync(cnts, 0, 2*N*sizeof(float), stream);
  k_count<<<(int)((E+255)/256),256,0,stream>>>(eidx, cnts, cntd, (int)E);
  k_dis<<<(int)((N+255)/256),256,0,stream>>>(cntd, dis, (int)N);

  // 2. edge indicator GEMM + segment sums (edge_feats built on the fly)
  (void)hipMemsetAsync(rs, 0, N*128*sizeof(float), stream);
  gemm_k<256,64,AM_EFEAT,EM_SCAT><<<(int)(E/64),256,0,stream>>>(
      nf,eidx, eattnW,eattnb,nullptr, rs, cs, (int)E);
  k_aei<<<(int)((N*16+255)/256),256,0,stream>>>(rs, cs, cnts, cntd, aei, (int)N);

  // 3. GCN conv 1
  gemm_k<128,64,AM_DENSE,EM_STORE><<<(int)((N+63)/64),256,0,stream>>>(
      nf,nullptr, gcn1W,nullptr,nullptr, lin1,nullptr,(int)N);
  (void)hipMemsetAsync(agg1, 0, N*64*sizeof(float), stream);
  k_scatter<64><<<(int)((E*16+255)/256),256,0,stream>>>(lin1, agg1, eidx, dis, (int)E);
  k_hcomb<64,true><<<(int)((N*16+255)/256),256,0,stream>>>(agg1, lin1, aei, dis, gcn1b, h1, (int)N);

  // 4. GCN conv 2
  gemm_k<64,128,AM_DENSE,EM_STORE><<<(int)((N+63)/64),256,0,stream>>>(
      h1,nullptr, gcn2W,nullptr,nullptr, lin2,nullptr,(int)N);
  (void)hipMemsetAsync(agg2, 0, N*128*sizeof(float), stream);
  k_scatter<128><<<(int)((E*32+255)/256),256,0,stream>>>(lin2, agg2, eidx, dis, (int)E);
  k_hcomb<128,false><<<(int)((N*32+255)/256),256,0,stream>>>(agg2, lin2, nullptr, dis, gcn2b, h2, (int)N);

  // 5. node attention (niB over lin2 — lin2 dead after hcomb)
  gemm_k<128,128,AM_DENSE,EM_BRELU><<<(int)((N+63)/64),256,0,stream>>>(
      h2,nullptr, nattnW,nattnb,nullptr, niB,nullptr,(int)N);

  // 6. fused node-indicator gate + edge MLP1
  k_ani_ef1<<<(int)(E/64),256,0,stream>>>(nf, niB, eidx, nredW, nredb, emlp1W, emlp1b, ef1);

  // 7. node head (nx over niB — niB dead after k_ani_ef1)
  gemm_k<128,64,AM_DENSE,EM_BNLK><<<(int)((N+63)/64),256,0,stream>>>(
      h2,nullptr, nlin1W,nbnb,nbng, nx,nullptr,(int)N);
  gemm_k<64,160,AM_DENSE,EM_STORE><<<(int)((N+63)/64),256,0,stream>>>(
      nx,nullptr, nlin2W,nullptr,nullptr, nlog,nullptr,(int)N);
  k_softmax_row<<<(int)((N+3)/4),256,0,stream>>>(nlog,(int)N);

  // 8. fused edge head: emlp2 -> elin1(BN,leaky) -> elin2 -> elog
  k_ehead<<<(int)(E/64),256,0,stream>>>(
      ef1, emlp2W, emlp2b, elin1W, ebng, ebnb, elin2W, elog);

  // 9. column softmax over E for edge logits (in place in d_out)
  (void)hipMemsetAsync(smalls, 0, 96*sizeof(float), stream);
  k_colmax<<<1024,256,0,stream>>>(elog, (uint32*)smalls, (int)E);
  k_colfix<<<1,32,0,stream>>>((const uint32*)smalls, smalls+64);
  k_colsum<<<1024,256,0,stream>>>(elog, smalls+64, smalls+32, (int)E);
  k_colnorm<<<(int)((E*27+255)/256),256,0,stream>>>(elog, smalls+64, smalls+32, (int)E);
}

// Round 5
// 2212.089 us; speedup vs baseline: 1.5998x; 1.5998x over previous
//
#include <hip/hip_runtime.h>

#define NN 100000
#define EE 320000

typedef unsigned int uint32;
typedef __attribute__((ext_vector_type(8))) short bf16x8;
typedef __attribute__((ext_vector_type(4))) float f32x4;

__device__ __forceinline__ float4 ld4(const float* p){ return *(const float4*)p; }
__device__ __forceinline__ void st4(float* p, const float4 v){ *(float4*)p = v; }
__device__ __forceinline__ float sigm(float x){ return 1.f/(1.f + expf(-x)); }
__device__ __forceinline__ short f2b(float f){
  union { float f; uint32 u; } v; v.f = f;
  uint32 r = (v.u + 0x7FFFu + ((v.u>>16)&1u)) >> 16;   // RNE
  return (short)r;
}

constexpr int AM_DENSE=0, AM_EFEAT=1;
constexpr int EM_STORE=0, EM_BRELU=1, EM_BNLK=2, EM_SCAT=3;

// ---------------------------------------------------------------------------
// Generic fp32 tiled GEMM (node path + eattn): 64 rows/block, BK=16.
// ---------------------------------------------------------------------------
template<int K,int NOUT,int AM,int EM>
__global__ __launch_bounds__(256) void gemm_k(
    const float* __restrict__ A,
    const int* __restrict__ eidx,
    const float* __restrict__ W, const float* __restrict__ bias,
    const float* __restrict__ bng,
    float* __restrict__ C, float* __restrict__ C2, int M)
{
  constexpr int CN = NOUT/16;
  __shared__ float As[16][68];
  __shared__ float Ws[16][NOUT];
  __shared__ int sidx[64], didx[64];
  const int t  = threadIdx.x;
  const int tx = t & 15, ty = t >> 4;
  const int row0 = blockIdx.x * 64;

  if constexpr (AM != AM_DENSE) {
    if (t < 64) {
      int e = row0 + t; int s=0,d=0;
      if (e < M){ s = eidx[2*e]; d = eidx[2*e+1]; }
      sidx[t]=s; didx[t]=d;
    }
    __syncthreads();
  }

  float acc[4][CN];
  #pragma unroll
  for (int i=0;i<4;i++)
    #pragma unroll
    for (int j=0;j<CN;j++) acc[i][j]=0.f;

  const int r_st  = t >> 2;
  const int kq_st = (t & 3) * 4;

  for (int k0=0;k0<K;k0+=16) {
    {
      float4 v = make_float4(0.f,0.f,0.f,0.f);
      const int gr = row0 + r_st;
      const int kk = k0 + kq_st;
      if (gr < M) {
        if constexpr (AM == AM_DENSE) {
          v = ld4(A + (size_t)gr*K + kk);
        } else {
          const int s=sidx[r_st], d=didx[r_st];
          if (kk < 128) v = ld4(A + (size_t)s*128 + kk);
          else {
            float4 a = ld4(A + (size_t)d*128 + (kk-128));
            float4 b = ld4(A + (size_t)s*128 + (kk-128));
            v.x=a.x-b.x; v.y=a.y-b.y; v.z=a.z-b.z; v.w=a.w-b.w;
          }
        }
      }
      As[kq_st+0][r_st]=v.x; As[kq_st+1][r_st]=v.y;
      As[kq_st+2][r_st]=v.z; As[kq_st+3][r_st]=v.w;
    }
    {
      constexpr int C4 = NOUT/4;
      for (int i=t;i<16*C4;i+=256){ int kk=i/C4, c4=(i%C4)*4;
        st4(&Ws[kk][c4], ld4(W + (size_t)(k0+kk)*NOUT + c4)); }
    }
    __syncthreads();
    #pragma unroll
    for (int kk=0;kk<16;kk++){
      float a0,a1,a2,a3;
      { const float4 av = *(const float4*)&As[kk][ty*4]; a0=av.x;a1=av.y;a2=av.z;a3=av.w; }
      float b[CN];
      if constexpr ((CN & 3) == 0) {
        #pragma unroll
        for (int j4=0;j4<CN;j4+=4){
          const float4 bv = *(const float4*)&Ws[kk][tx*CN+j4];
          b[j4]=bv.x;b[j4+1]=bv.y;b[j4+2]=bv.z;b[j4+3]=bv.w; }
      } else {
        #pragma unroll
        for (int j=0;j<CN;j++) b[j]=Ws[kk][tx*CN+j];
      }
      #pragma unroll
      for (int j=0;j<CN;j++){
        acc[0][j]=fmaf(a0,b[j],acc[0][j]);
        acc[1][j]=fmaf(a1,b[j],acc[1][j]);
        acc[2][j]=fmaf(a2,b[j],acc[2][j]);
        acc[3][j]=fmaf(a3,b[j],acc[3][j]);
      }
    }
    __syncthreads();
  }

  float sc[CN], sh[CN];
  if constexpr (EM==EM_BNLK) {
    const float r_ = rsqrtf(1.f + 1e-5f);
    #pragma unroll
    for (int j=0;j<CN;j++){ int c=tx*CN+j; sc[j]=bng[c]*r_; sh[j]=bias[c]; }
  }
  #pragma unroll
  for (int i=0;i<4;i++){
    const int rr = ty*4+i;
    const int r  = row0 + rr;
    if (r >= M) continue;
    #pragma unroll
    for (int j=0;j<CN;j++){
      const int c = tx*CN+j;
      float v = acc[i][j];
      if constexpr (EM==EM_BRELU) v = fmaxf(v + bias[c], 0.f);
      else if constexpr (EM==EM_BNLK){ float x = fmaf(v, sc[j], sh[j]); v = (x>0.f)? x : 0.2f*x; }
      if constexpr (EM==EM_SCAT){
        v += bias[c];
        atomicAdd(&C [(size_t)sidx[rr]*NOUT + c], v);
        atomicAdd(&C2[(size_t)didx[rr]*NOUT + c], v);
      } else {
        C[(size_t)r*NOUT + c] = v;
      }
    }
  }
}

// ---------------------------------------------------------------------------
// Weight transpose + cast: Wt[NP][K] bf16 <- W[K][N] fp32 (rows n>=N zeroed)
// ---------------------------------------------------------------------------
__global__ void k_twt(const float* __restrict__ W, short* __restrict__ Wt,
                      int K, int N, int NP){
  int idx = blockIdx.x*256 + threadIdx.x;
  if (idx >= NP*K) return;
  int n = idx / K, k = idx - n*K;
  Wt[idx] = (n<N)? f2b(W[(size_t)k*N + n]) : (short)0;
}

// ---------------------------------------------------------------------------
// MFMA phase helper: C(64 x NCT*16) += As(64 x KTOT, bf16 LDS) @ Wt^T
// Wt is [ncols][KTOT] bf16 row-major (pre-transposed). 4 waves, wave w owns
// rows [w*16, w*16+16). Fragment maps: A row=lane&15, B col=lane&15,
// k = (lane>>4)*8 + j  (same map both sides -> k-permutation invariant).
// Per 32-k slab each column needs 32 shorts = 4 x float4 (q = 0..3).
// ---------------------------------------------------------------------------
template<int KTOT, int NCT>
__device__ __forceinline__ void mm_phase(
    const short* __restrict__ Wt,
    short (*As)[264], short (*Bs)[40],
    int t, int lane, int arow, int kgrp, f32x4* acc)
{
  constexpr int KS = KTOT/32;
  constexpr int NC = NCT*16;
  #pragma unroll
  for (int kb=0; kb<KS; ++kb){
    for (int i=t; i<NC*4; i+=256){
      int col = i>>2, q = i&3;
      const float4 w = *(const float4*)(Wt + (size_t)col*KTOT + kb*32 + q*8);
      *(float4*)&Bs[col][q*8] = w;
    }
    __syncthreads();
    const bf16x8 a = *(const bf16x8*)&As[arow][kb*32 + kgrp*8];
    #pragma unroll
    for (int ct=0; ct<NCT; ++ct){
      const bf16x8 b = *(const bf16x8*)&Bs[ct*16 + (lane&15)][kgrp*8];
      acc[ct] = __builtin_amdgcn_mfma_f32_16x16x32_bf16(a, b, acc[ct], 0, 0, 0);
    }
    __syncthreads();
  }
}

// ---------------------------------------------------------------------------
// Fused edge mega-kernel (bf16 MFMA):
//   G   = sigmoid(concat(ni[s],ni[d]) @ nredW + nredb)          [regs]
//   ef1 = relu(concat(nf[s],nf[d]-nf[s]) @ emlp1W + emlp1b)*G   [LDS]
//   ef2 = relu(ef1 @ emlp2W + emlp2b)                           [LDS]
//   ex  = leakyBN(ef2 @ elin1W; ebng, ebnb)                     [LDS]
//   elog= ex @ elin2W   -> d_out (fp32)
// ---------------------------------------------------------------------------
__global__ __launch_bounds__(256) void k_edge(
  const float* __restrict__ nf, const float* __restrict__ ni,
  const int* __restrict__ eidx,
  const short* __restrict__ wt_nred, const float* __restrict__ nredb,
  const short* __restrict__ wt_e1,   const float* __restrict__ e1b,
  const short* __restrict__ wt_e2,   const float* __restrict__ e2b,
  const short* __restrict__ wt_l1,   const float* __restrict__ ebng, const float* __restrict__ ebnb,
  const short* __restrict__ wt_l2,
  float* __restrict__ elog)
{
  __shared__ short As[64][264];    // 33792 B (A tiles / ef1 / ef2 / ex / out-bounce)
  __shared__ short Bs[256][40];    // 20480 B (per-k-step weight slab)
  __shared__ int sidx[64], didx[64];
  const int t = threadIdx.x;
  const int lane = t & 63, wave = t >> 6;
  const int row0 = blockIdx.x * 64;
  const int kgrp = lane >> 4;
  const int arow = wave*16 + (lane & 15);   // A-fragment row for this lane
  const int crow = wave*16 + kgrp*4;        // C-fragment base row for this lane

  if (t < 64){ sidx[t]=eidx[2*(row0+t)]; didx[t]=eidx[2*(row0+t)+1]; }
  __syncthreads();

  const int srow = t & 63, seg = t >> 6;    // staging: thread loads 64 floats of one row

  // ---- phase 1: gate GEMM, A = concat(ni[s], ni[d]) ----
  {
    const float* src = (seg<2)? (ni + (size_t)sidx[srow]*128 + seg*64)
                              : (ni + (size_t)didx[srow]*128 + (seg-2)*64);
    short* dst = &As[srow][seg*64];
    #pragma unroll
    for (int p=0;p<8;p++){
      float4 u = ld4(src + p*8), v = ld4(src + p*8 + 4);
      bf16x8 o;
      o[0]=f2b(u.x);o[1]=f2b(u.y);o[2]=f2b(u.z);o[3]=f2b(u.w);
      o[4]=f2b(v.x);o[5]=f2b(v.y);o[6]=f2b(v.z);o[7]=f2b(v.w);
      *(bf16x8*)(dst + p*8) = o;
    }
  }
  f32x4 acc1[8];
  #pragma unroll
  for (int j=0;j<8;j++) acc1[j] = (f32x4){0.f,0.f,0.f,0.f};
  mm_phase<256,8>(wt_nred, As, Bs, t, lane, arow, kgrp, acc1);

  float g[8][4];
  #pragma unroll
  for (int ct=0;ct<8;ct++){
    const float bb = nredb[ct*16 + (lane&15)];
    #pragma unroll
    for (int r=0;r<4;r++) g[ct][r] = sigm(acc1[ct][r] + bb);
  }

  // ---- phase 2: emlp1 GEMM, A = concat(nf[s], nf[d]-nf[s]) ----
  {
    short* dst = &As[srow][seg*64];
    const int s = sidx[srow], d = didx[srow];
    #pragma unroll
    for (int p=0;p<8;p++){
      float4 u, v;
      if (seg < 2){
        u = ld4(nf + (size_t)s*128 + seg*64 + p*8);
        v = ld4(nf + (size_t)s*128 + seg*64 + p*8 + 4);
      } else {
        float4 ua = ld4(nf + (size_t)d*128 + (seg-2)*64 + p*8);
        float4 ub = ld4(nf + (size_t)s*128 + (seg-2)*64 + p*8);
        float4 va = ld4(nf + (size_t)d*128 + (seg-2)*64 + p*8 + 4);
        float4 vb = ld4(nf + (size_t)s*128 + (seg-2)*64 + p*8 + 4);
        u.x=ua.x-ub.x; u.y=ua.y-ub.y; u.z=ua.z-ub.z; u.w=ua.w-ub.w;
        v.x=va.x-vb.x; v.y=va.y-vb.y; v.z=va.z-vb.z; v.w=va.w-vb.w;
      }
      bf16x8 o;
      o[0]=f2b(u.x);o[1]=f2b(u.y);o[2]=f2b(u.z);o[3]=f2b(u.w);
      o[4]=f2b(v.x);o[5]=f2b(v.y);o[6]=f2b(v.z);o[7]=f2b(v.w);
      *(bf16x8*)(dst + p*8) = o;
    }
  }
  f32x4 acc2[8];
  #pragma unroll
  for (int j=0;j<8;j++) acc2[j] = (f32x4){0.f,0.f,0.f,0.f};
  mm_phase<256,8>(wt_e1, As, Bs, t, lane, arow, kgrp, acc2);

  // ef1 = relu(acc2+b)*G -> As (own rows, cols 0..127)
  #pragma unroll
  for (int ct=0;ct<8;ct++){
    const int col = ct*16 + (lane&15);
    const float bb = e1b[col];
    #pragma unroll
    for (int r=0;r<4;r++)
      As[crow+r][col] = f2b(fmaxf(acc2[ct][r] + bb, 0.f) * g[ct][r]);
  }

  // ---- phase 3: emlp2 GEMM (128 -> 256) ----
  f32x4 acc3[16];
  #pragma unroll
  for (int j=0;j<16;j++) acc3[j] = (f32x4){0.f,0.f,0.f,0.f};
  mm_phase<128,16>(wt_e2, As, Bs, t, lane, arow, kgrp, acc3);
  #pragma unroll
  for (int ct=0;ct<16;ct++){
    const int col = ct*16 + (lane&15);
    const float bb = e2b[col];
    #pragma unroll
    for (int r=0;r<4;r++)
      As[crow+r][col] = f2b(fmaxf(acc3[ct][r] + bb, 0.f));
  }

  // ---- phase 4: elin1 + BN + leaky (256 -> 128) ----
  f32x4 acc4[8];
  #pragma unroll
  for (int j=0;j<8;j++) acc4[j] = (f32x4){0.f,0.f,0.f,0.f};
  mm_phase<256,8>(wt_l1, As, Bs, t, lane, arow, kgrp, acc4);
  {
    const float r_ = rsqrtf(1.f + 1e-5f);
    #pragma unroll
    for (int ct=0;ct<8;ct++){
      const int col = ct*16 + (lane&15);
      const float sc = ebng[col]*r_, sh = ebnb[col];
      #pragma unroll
      for (int r=0;r<4;r++){
        float x = fmaf(acc4[ct][r], sc, sh);
        As[crow+r][col] = f2b((x>0.f)? x : 0.2f*x);
      }
    }
  }

  // ---- phase 5: elin2 (128 -> 27, padded 32) ----
  f32x4 acc5[2];
  acc5[0] = (f32x4){0.f,0.f,0.f,0.f}; acc5[1] = (f32x4){0.f,0.f,0.f,0.f};
  mm_phase<128,2>(wt_l2, As, Bs, t, lane, arow, kgrp, acc5);

  // bounce through LDS for coalesced fp32 store
  float* Lb = (float*)&As[0][0];   // [64][28]
  #pragma unroll
  for (int ct=0;ct<2;ct++){
    const int col = ct*16 + (lane&15);
    if (col < 27){
      #pragma unroll
      for (int r=0;r<4;r++) Lb[(crow+r)*28 + col] = acc5[ct][r];
    }
  }
  __syncthreads();
  for (int i=t; i<64*27; i+=256){
    int rr = i/27, cc = i - rr*27;
    elog[(size_t)(row0+rr)*27 + cc] = Lb[rr*28 + cc];
  }
}

// ---------------------------- small kernels --------------------------------
__global__ void k_count(const int* __restrict__ eidx, float* a, float* b, int E){
  int e = blockIdx.x*256+threadIdx.x; if (e>=E) return;
  atomicAdd(&a[eidx[2*e]],   1.f);
  atomicAdd(&b[eidx[2*e+1]], 1.f);
}
__global__ void k_dis(const float* __restrict__ cd, float* __restrict__ dis, int n){
  int i=blockIdx.x*256+threadIdx.x; if(i>=n)return;
  dis[i]=rsqrtf(cd[i]+1.f);
}
__global__ void k_aei(const float* __restrict__ rs, const float* __restrict__ cs,
                      const float* __restrict__ cns, const float* __restrict__ cnd,
                      float* __restrict__ aei, int n){
  int idx=blockIdx.x*256+threadIdx.x; if(idx>=n*16)return;
  int i=idx>>4, q=(idx&15)*4;
  float ir=1.f/fmaxf(cns[i],1.f), ic=1.f/fmaxf(cnd[i],1.f);
  float4 a=ld4(rs+(size_t)i*64+q), b=ld4(cs+(size_t)i*64+q);
  float4 o;
  o.x=sigm(a.x*ir*(b.x*ic)); o.y=sigm(a.y*ir*(b.y*ic));
  o.z=sigm(a.z*ir*(b.z*ic)); o.w=sigm(a.w*ir*(b.w*ic));
  st4(aei+(size_t)i*64+q, o);
}
template<int NC, bool AEI>
__global__ void k_hcomb(const float* __restrict__ agg, const float* __restrict__ lin,
                        const float* __restrict__ aei, const float* __restrict__ dis,
                        const float* __restrict__ bias, float* __restrict__ h, int n){
  constexpr int Q = NC/4;
  int idx=blockIdx.x*256+threadIdx.x; if(idx>=n*Q)return;
  int i=idx/Q, q=(idx%Q)*4;
  float d2=dis[i]; d2*=d2;
  float4 ag=ld4(agg+(size_t)i*NC+q), ln=ld4(lin+(size_t)i*NC+q), b=ld4(bias+q);
  float4 o;
  o.x=fmaxf(fmaf(ln.x,d2,ag.x)+b.x,0.f); o.y=fmaxf(fmaf(ln.y,d2,ag.y)+b.y,0.f);
  o.z=fmaxf(fmaf(ln.z,d2,ag.z)+b.z,0.f); o.w=fmaxf(fmaf(ln.w,d2,ag.w)+b.w,0.f);
  if (AEI){ float4 m=ld4(aei+(size_t)i*NC+q); o.x*=m.x;o.y*=m.y;o.z*=m.z;o.w*=m.w; }
  st4(h+(size_t)i*NC+q,o);
}
template<int NC>
__global__ void k_scatter(const float* __restrict__ lin, float* __restrict__ agg,
                          const int* __restrict__ eidx, const float* __restrict__ dis, int E){
  constexpr int Q=NC/4;
  int idx=blockIdx.x*256+threadIdx.x; if (idx>=E*Q) return;
  int e=idx/Q, q=(idx%Q)*4;
  int s=eidx[2*e], d=eidx[2*e+1];
  float w=dis[s]*dis[d];
  float4 v=ld4(lin+(size_t)s*NC+q);
  float* p=agg+(size_t)d*NC+q;
  atomicAdd(p+0,v.x*w); atomicAdd(p+1,v.y*w); atomicAdd(p+2,v.z*w); atomicAdd(p+3,v.w*w);
}
__global__ __launch_bounds__(256) void k_softmax_row(float* __restrict__ x, int M){
  const int wave = threadIdx.x>>6, lane = threadIdx.x&63;
  const int r = blockIdx.x*4 + wave; if (r>=M) return;
  float* p = x + (size_t)r*160;
  float v0 = p[lane], v1 = p[64+lane];
  float v2 = (lane<32)? p[128+lane] : -3.4e38f;
  float m = fmaxf(fmaxf(v0,v1),v2);
  for (int o=32;o;o>>=1) m = fmaxf(m, __shfl_xor(m,o));
  float e0=expf(v0-m), e1=expf(v1-m), e2=(lane<32)?expf(v2-m):0.f;
  float s=e0+e1+e2;
  for (int o=32;o;o>>=1) s += __shfl_xor(s,o);
  float inv = 1.f/s;
  p[lane]=e0*inv; p[64+lane]=e1*inv; if(lane<32)p[128+lane]=e2*inv;
}
__global__ void k_colmax(const float* __restrict__ x, uint32* __restrict__ cmax_u, int E){
  __shared__ float red[8][32];
  const int t=threadIdx.x, col=t&31, seg=t>>5;
  float m = -3.4e38f;
  if (col < 27)
    for (int r = blockIdx.x*8 + seg; r < E; r += gridDim.x*8)
      m = fmaxf(m, x[(size_t)r*27+col]);
  red[seg][col]=m; __syncthreads();
  if (t<32){
    float mm=red[0][t];
    #pragma unroll
    for (int s2=1;s2<8;s2++) mm=fmaxf(mm,red[s2][t]);
    if (t<27){
      uint32 u=__float_as_uint(mm);
      u = (u&0x80000000u)? ~u : (u|0x80000000u);
      atomicMax(&cmax_u[t], u);
    }
  }
}
__global__ void k_colfix(const uint32* __restrict__ cmax_u, float* __restrict__ cmaxf){
  int t=threadIdx.x; if (t>=27) return;
  uint32 u=cmax_u[t];
  cmaxf[t] = (u&0x80000000u)? __uint_as_float(u&0x7FFFFFFFu) : __uint_as_float(~u);
}
__global__ void k_colsum(const float* __restrict__ x, const float* __restrict__ cmaxf,
                         float* __restrict__ csum, int E){
  __shared__ float red[8][32];
  const int t=threadIdx.x, col=t&31, seg=t>>5;
  float s = 0.f;
  if (col < 27){
    const float cm = cmaxf[col];
    for (int r = blockIdx.x*8 + seg; r < E; r += gridDim.x*8)
      s += expf(x[(size_t)r*27+col] - cm);
  }
  red[seg][col]=s; __syncthreads();
  if (t<32){
    float ss=red[0][t];
    #pragma unroll
    for (int s2=1;s2<8;s2++) ss+=red[s2][t];
    if (t<27) atomicAdd(&csum[t], ss);
  }
}
__global__ void k_colnorm(float* __restrict__ x, const float* __restrict__ cmaxf,
                          const float* __restrict__ csum, int E){
  int idx=blockIdx.x*256+threadIdx.x;
  if (idx >= E*27) return;
  int c = idx - (idx/27)*27;
  x[idx] = expf(x[idx]-cmaxf[c]) / csum[c];
}

// ---------------------------------------------------------------------------
extern "C" void kernel_launch(void* const* d_in, const int* in_sizes, int n_in,
                              void* d_out, int out_size, void* d_ws, size_t ws_size,
                              hipStream_t stream)
{
  const float* nf     = (const float*)d_in[0];
  const int*   eidx   = (const int*)  d_in[1];
  const float* gcn1W  = (const float*)d_in[2];
  const float* gcn1b  = (const float*)d_in[3];
  const float* gcn2W  = (const float*)d_in[4];
  const float* gcn2b  = (const float*)d_in[5];
  const float* eattnW = (const float*)d_in[6];
  const float* eattnb = (const float*)d_in[7];
  const float* nattnW = (const float*)d_in[8];
  const float* nattnb = (const float*)d_in[9];
  const float* nredW  = (const float*)d_in[10];
  const float* nredb  = (const float*)d_in[11];
  const float* emlp1W = (const float*)d_in[12];
  const float* emlp1b = (const float*)d_in[13];
  const float* emlp2W = (const float*)d_in[14];
  const float* emlp2b = (const float*)d_in[15];
  const float* nlin1W = (const float*)d_in[16];
  const float* nbng   = (const float*)d_in[17];
  const float* nbnb   = (const float*)d_in[18];
  const float* nlin2W = (const float*)d_in[19];
  const float* elin1W = (const float*)d_in[20];
  const float* ebng   = (const float*)d_in[21];
  const float* ebnb   = (const float*)d_in[22];
  const float* elin2W = (const float*)d_in[23];
  (void)in_sizes; (void)n_in; (void)out_size; (void)ws_size;

  const size_t N = NN, E = EE;
  float* out  = (float*)d_out;
  float* nlog = out;               // N*160
  float* elog = out + N*160;       // E*27

  // ---- workspace plan: ~N*516 floats + 264 KB ≈ 207 MB ----
  float* ws   = (float*)d_ws;
  float* agg2 = ws;                   // N*128 ; -> h2 in place
  float* h2   = agg2;
  float* lin2 = ws + N*128;           // N*128 ; -> niB -> nx
  float* niB  = lin2;
  float* nx   = lin2;
  float* rs   = ws + N*256;           // N*64 ; -> aei in place
  float* aei  = rs;
  float* cs   = ws + N*320;           // N*64
  float* lin1 = ws + N*384;           // N*64
  float* agg1 = ws + N*448;           // N*64 ; -> h1 in place
  float* h1   = agg1;
  float* cnts = ws + N*512;           // N
  float* cntd = cnts + N;             // N
  float* dis  = cnts + 2*N;           // N
  float* smalls = ws + N*515;         // 96
  short* wtb  = (short*)(ws + N*515 + 128);
  short* wt_nred = wtb;               // 128*256
  short* wt_e1   = wtb + 32768;       // 128*256
  short* wt_e2   = wtb + 65536;       // 256*128
  short* wt_l1   = wtb + 98304;       // 128*256
  short* wt_l2   = wtb + 131072;      // 32*128

  // 0. bf16 weight transposes (independent, tiny)
  k_twt<<<128,256,0,stream>>>(nredW,  wt_nred, 256, 128, 128);
  k_twt<<<128,256,0,stream>>>(emlp1W, wt_e1,   256, 128, 128);
  k_twt<<<128,256,0,stream>>>(emlp2W, wt_e2,   128, 256, 256);
  k_twt<<<128,256,0,stream>>>(elin1W, wt_l1,   256, 128, 128);
  k_twt<<<16, 256,0,stream>>>(elin2W, wt_l2,   128, 27,  32);

  // 1. degrees
  (void)hipMemsetAsync(cnts, 0, 2*N*sizeof(float), stream);
  k_count<<<(int)((E+255)/256),256,0,stream>>>(eidx, cnts, cntd, (int)E);
  k_dis<<<(int)((N+255)/256),256,0,stream>>>(cntd, dis, (int)N);

  // 2. edge indicator GEMM + segment sums
  (void)hipMemsetAsync(rs, 0, N*128*sizeof(float), stream);
  gemm_k<256,64,AM_EFEAT,EM_SCAT><<<(int)(E/64),256,0,stream>>>(
      nf,eidx, eattnW,eattnb,nullptr, rs, cs, (int)E);
  k_aei<<<(int)((N*16+255)/256),256,0,stream>>>(rs, cs, cnts, cntd, aei, (int)N);

  // 3. GCN conv 1
  gemm_k<128,64,AM_DENSE,EM_STORE><<<(int)((N+63)/64),256,0,stream>>>(
      nf,nullptr, gcn1W,nullptr,nullptr, lin1,nullptr,(int)N);
  (void)hipMemsetAsync(agg1, 0, N*64*sizeof(float), stream);
  k_scatter<64><<<(int)((E*16+255)/256),256,0,stream>>>(lin1, agg1, eidx, dis, (int)E);
  k_hcomb<64,true><<<(int)((N*16+255)/256),256,0,stream>>>(agg1, lin1, aei, dis, gcn1b, h1, (int)N);

  // 4. GCN conv 2
  gemm_k<64,128,AM_DENSE,EM_STORE><<<(int)((N+63)/64),256,0,stream>>>(
      h1,nullptr, gcn2W,nullptr,nullptr, lin2,nullptr,(int)N);
  (void)hipMemsetAsync(agg2, 0, N*128*sizeof(float), stream);
  k_scatter<128><<<(int)((E*32+255)/256),256,0,stream>>>(lin2, agg2, eidx, dis, (int)E);
  k_hcomb<128,false><<<(int)((N*32+255)/256),256,0,stream>>>(agg2, lin2, nullptr, dis, gcn2b, h2, (int)N);

  // 5. node attention
  gemm_k<128,128,AM_DENSE,EM_BRELU><<<(int)((N+63)/64),256,0,stream>>>(
      h2,nullptr, nattnW,nattnb,nullptr, niB,nullptr,(int)N);

  // 6. fused edge chain (bf16 MFMA): gate+emlp1+emlp2+elin1+elin2 -> elog
  k_edge<<<(int)(E/64),256,0,stream>>>(
      nf, niB, eidx,
      wt_nred, nredb, wt_e1, emlp1b, wt_e2, emlp2b,
      wt_l1, ebng, ebnb, wt_l2, elog);

  // 7. node head (nx over niB — niB dead after k_edge)
  gemm_k<128,64,AM_DENSE,EM_BNLK><<<(int)((N+63)/64),256,0,stream>>>(
      h2,nullptr, nlin1W,nbnb,nbng, nx,nullptr,(int)N);
  gemm_k<64,160,AM_DENSE,EM_STORE><<<(int)((N+63)/64),256,0,stream>>>(
      nx,nullptr, nlin2W,nullptr,nullptr, nlog,nullptr,(int)N);
  k_softmax_row<<<(int)((N+3)/4),256,0,stream>>>(nlog,(int)N);

  // 8. column softmax over E for edge logits (in place in d_out)
  (void)hipMemsetAsync(smalls, 0, 96*sizeof(float), stream);
  k_colmax<<<1024,256,0,stream>>>(elog, (uint32*)smalls, (int)E);
  k_colfix<<<1,32,0,stream>>>((const uint32*)smalls, smalls+64);
  k_colsum<<<1024,256,0,stream>>>(elog, smalls+64, smalls+32, (int)E);
  k_colnorm<<<(int)((E*27+255)/256),256,0,stream>>>(elog, smalls+64, smalls+32, (int)E);
}

// Round 6
// 970.135 us; speedup vs baseline: 3.6478x; 2.2802x over previous
//
#include <hip/hip_runtime.h>

#define NN 100000
#define EE 320000

typedef unsigned int uint32;
typedef __attribute__((ext_vector_type(8))) short bf16x8;
typedef __attribute__((ext_vector_type(4))) float f32x4;

__device__ __forceinline__ float4 ld4(const float* p){ return *(const float4*)p; }
__device__ __forceinline__ void st4(float* p, const float4 v){ *(float4*)p = v; }
__device__ __forceinline__ float sigm(float x){ return 1.f/(1.f + expf(-x)); }
__device__ __forceinline__ short f2b(float f){
  union { float f; uint32 u; } v; v.f = f;
  uint32 r = (v.u + 0x7FFFu + ((v.u>>16)&1u)) >> 16;   // RNE
  return (short)r;
}

constexpr int EM_STORE=0, EM_BRELU=1, EM_BNLK=2;

// ---------------------------------------------------------------------------
// Generic fp32 tiled GEMM (node path): 64 rows/block, BK=16, 256 threads.
// ---------------------------------------------------------------------------
template<int K,int NOUT,int EM>
__global__ __launch_bounds__(256) void gemm_k(
    const float* __restrict__ A,
    const float* __restrict__ W, const float* __restrict__ bias,
    const float* __restrict__ bng,
    float* __restrict__ C, int M)
{
  constexpr int CN = NOUT/16;
  __shared__ float As[16][68];
  __shared__ float Ws[16][NOUT];
  const int t  = threadIdx.x;
  const int tx = t & 15, ty = t >> 4;
  const int row0 = blockIdx.x * 64;

  float acc[4][CN];
  #pragma unroll
  for (int i=0;i<4;i++)
    #pragma unroll
    for (int j=0;j<CN;j++) acc[i][j]=0.f;

  const int r_st  = t >> 2;
  const int kq_st = (t & 3) * 4;

  for (int k0=0;k0<K;k0+=16) {
    {
      float4 v = make_float4(0.f,0.f,0.f,0.f);
      const int gr = row0 + r_st;
      if (gr < M) v = ld4(A + (size_t)gr*K + k0 + kq_st);
      As[kq_st+0][r_st]=v.x; As[kq_st+1][r_st]=v.y;
      As[kq_st+2][r_st]=v.z; As[kq_st+3][r_st]=v.w;
    }
    {
      constexpr int C4 = NOUT/4;
      for (int i=t;i<16*C4;i+=256){ int kk=i/C4, c4=(i%C4)*4;
        st4(&Ws[kk][c4], ld4(W + (size_t)(k0+kk)*NOUT + c4)); }
    }
    __syncthreads();
    #pragma unroll
    for (int kk=0;kk<16;kk++){
      float a0,a1,a2,a3;
      { const float4 av = *(const float4*)&As[kk][ty*4]; a0=av.x;a1=av.y;a2=av.z;a3=av.w; }
      float b[CN];
      if constexpr ((CN & 3) == 0) {
        #pragma unroll
        for (int j4=0;j4<CN;j4+=4){
          const float4 bv = *(const float4*)&Ws[kk][tx*CN+j4];
          b[j4]=bv.x;b[j4+1]=bv.y;b[j4+2]=bv.z;b[j4+3]=bv.w; }
      } else {
        #pragma unroll
        for (int j=0;j<CN;j++) b[j]=Ws[kk][tx*CN+j];
      }
      #pragma unroll
      for (int j=0;j<CN;j++){
        acc[0][j]=fmaf(a0,b[j],acc[0][j]);
        acc[1][j]=fmaf(a1,b[j],acc[1][j]);
        acc[2][j]=fmaf(a2,b[j],acc[2][j]);
        acc[3][j]=fmaf(a3,b[j],acc[3][j]);
      }
    }
    __syncthreads();
  }

  float sc[CN], sh[CN];
  if constexpr (EM==EM_BNLK) {
    const float r_ = rsqrtf(1.f + 1e-5f);
    #pragma unroll
    for (int j=0;j<CN;j++){ int c=tx*CN+j; sc[j]=bng[c]*r_; sh[j]=bias[c]; }
  }
  #pragma unroll
  for (int i=0;i<4;i++){
    const int r  = row0 + ty*4+i;
    if (r >= M) continue;
    #pragma unroll
    for (int j=0;j<CN;j++){
      const int c = tx*CN+j;
      float v = acc[i][j];
      if constexpr (EM==EM_BRELU) v = fmaxf(v + bias[c], 0.f);
      else if constexpr (EM==EM_BNLK){ float x = fmaf(v, sc[j], sh[j]); v = (x>0.f)? x : 0.2f*x; }
      C[(size_t)r*NOUT + c] = v;
    }
  }
}

// ---------------------------------------------------------------------------
// CSR build: histogram -> scan -> fill
// ---------------------------------------------------------------------------
__global__ void k_hist(const int* __restrict__ eidx, int* cntS, int* cntD, int E){
  int e = blockIdx.x*256+threadIdx.x; if (e>=E) return;
  atomicAdd(&cntS[eidx[2*e]], 1);
  atomicAdd(&cntD[eidx[2*e+1]], 1);
}
__global__ void k_scan_sum(const int* __restrict__ cnt, int* bsum, int n){
  __shared__ int red[256];
  const int b=blockIdx.x, t=threadIdx.x;
  int s=0;
  for (int i=b*1024+t; i<n && i<(b+1)*1024; i+=256) s += cnt[i];
  red[t]=s; __syncthreads();
  for (int o=128;o;o>>=1){ if(t<o) red[t]+=red[t+o]; __syncthreads(); }
  if (t==0) bsum[b]=red[0];
}
__global__ void k_scan_top(int* bsum, int nb){   // 1 block, nb<=256
  __shared__ int sh[256];
  const int t=threadIdx.x;
  int v=(t<nb)?bsum[t]:0;
  sh[t]=v; __syncthreads();
  for (int o=1;o<256;o<<=1){
    int u=0; if(t>=o) u=sh[t-o];
    __syncthreads();
    sh[t]+=u;
    __syncthreads();
  }
  if (t<nb) bsum[t]=sh[t]-v;   // exclusive
}
__global__ void k_scan_out(const int* __restrict__ cnt, const int* __restrict__ bofs,
                           int* __restrict__ off, int n){
  __shared__ int sh[256];
  const int b=blockIdx.x, t=threadIdx.x;
  const int base=b*1024+t*4;
  int c0=0,c1=0,c2=0,c3=0;
  if(base+0<n)c0=cnt[base+0];
  if(base+1<n)c1=cnt[base+1];
  if(base+2<n)c2=cnt[base+2];
  if(base+3<n)c3=cnt[base+3];
  int s=c0+c1+c2+c3;
  sh[t]=s; __syncthreads();
  int v=s;
  for (int o=1;o<256;o<<=1){
    int u=0; if(t>=o) u=sh[t-o];
    __syncthreads();
    sh[t]+=u;
    __syncthreads();
  }
  const int tofs = sh[t]-v + bofs[b];
  if(base+0<n) off[base+0]=tofs;
  if(base+1<n) off[base+1]=tofs+c0;
  if(base+2<n) off[base+2]=tofs+c0+c1;
  if(base+3<n) off[base+3]=tofs+c0+c1+c2;
}
__global__ void k_copyoff(const int* __restrict__ off, int* __restrict__ cur, int n, int E){
  int i=blockIdx.x*256+threadIdx.x;
  if (i<n) cur[i]=off[i];
  if (i==0) cur[n]=0;        // unused; keep deterministic
}
__global__ void k_setend(int* offS, int* offD, int n, int E){
  if (threadIdx.x==0 && blockIdx.x==0){ offS[n]=E; offD[n]=E; }
}
__global__ void k_fill(const int* __restrict__ eidx, int* curS, int* curD,
                       int* __restrict__ csrS, int* __restrict__ csrD, int E){
  int e=blockIdx.x*256+threadIdx.x; if (e>=E) return;
  const int s=eidx[2*e], d=eidx[2*e+1];
  csrS[atomicAdd(&curS[s],1)] = d;
  csrD[atomicAdd(&curD[d],1)] = s;
}
__global__ void k_dis(const int* __restrict__ cntD, float* __restrict__ dis, int n){
  int i=blockIdx.x*256+threadIdx.x; if(i>=n)return;
  dis[i]=rsqrtf((float)cntD[i]+1.f);
}

// ---------------------------------------------------------------------------
// Wcat = [Wbot | Wd | gcn1W]  (128 x 192 fp32)
// ---------------------------------------------------------------------------
__global__ void k_wprep(const float* __restrict__ eattnW, const float* __restrict__ gcn1W,
                        float* __restrict__ Wcat){
  int idx=blockIdx.x*256+threadIdx.x; if (idx>=128*192) return;
  int k=idx/192, c=idx-k*192;
  float v;
  if (c<64)       v = eattnW[(size_t)(128+k)*64 + c];
  else if (c<128) v = eattnW[(size_t)k*64 + (c-64)] - eattnW[(size_t)(128+k)*64 + (c-64)];
  else            v = gcn1W[(size_t)k*64 + (c-128)];
  Wcat[idx]=v;
}

// ---------------------------------------------------------------------------
// CSR gather-sum: out[n][0..NC) = sum_{j in seg(n)} src[csr[j]][colbase..]
// ---------------------------------------------------------------------------
template<int NC>
__global__ void k_gather(const float* __restrict__ src, int stride, int colbase,
                         const int* __restrict__ off, const int* __restrict__ csr,
                         float* __restrict__ out, int n){
  constexpr int TPN = NC/4;
  const int t=threadIdx.x;
  const int node = blockIdx.x*(256/TPN) + t/TPN; if (node>=n) return;
  const int cq = (t%TPN)*4;
  const int j1=off[node+1];
  float4 acc = make_float4(0.f,0.f,0.f,0.f);
  for (int j=off[node]; j<j1; ++j){
    const float4 v = ld4(src + (size_t)csr[j]*stride + colbase + cq);
    acc.x+=v.x; acc.y+=v.y; acc.z+=v.z; acc.w+=v.w;
  }
  st4(out + (size_t)node*NC + cq, acc);
}

// aei = sigmoid(row*col); row=(cS*(U+b)+Q)/max(cS,1), col=(cD*(T+b)+S)/max(cD,1)
__global__ void k_aei3(const float* __restrict__ TUL, const float* __restrict__ Q,
                       const float* __restrict__ S, const int* __restrict__ cntS,
                       const int* __restrict__ cntD, const float* __restrict__ bias,
                       float* __restrict__ aei, int n){
  int idx=blockIdx.x*256+threadIdx.x; if (idx>=n*16) return;
  const int i=idx>>4, cq=(idx&15)*4;
  const float cS=(float)cntS[i], cD=(float)cntD[i];
  const float iS=1.f/fmaxf(cS,1.f), iD=1.f/fmaxf(cD,1.f);
  const float* tul = TUL + (size_t)i*192;
  const float4 T4=ld4(tul+cq), U4=ld4(tul+64+cq);
  const float4 Q4=ld4(Q+(size_t)i*64+cq), S4=ld4(S+(size_t)i*64+cq), b4=ld4(bias+cq);
  float4 o;
  o.x=sigm(((cS*(U4.x+b4.x)+Q4.x)*iS) * ((cD*(T4.x+b4.x)+S4.x)*iD));
  o.y=sigm(((cS*(U4.y+b4.y)+Q4.y)*iS) * ((cD*(T4.y+b4.y)+S4.y)*iD));
  o.z=sigm(((cS*(U4.z+b4.z)+Q4.z)*iS) * ((cD*(T4.z+b4.z)+S4.z)*iD));
  o.w=sigm(((cS*(U4.w+b4.w)+Q4.w)*iS) * ((cD*(T4.w+b4.w)+S4.w)*iD));
  st4(aei + (size_t)i*64 + cq, o);
}

// GCN aggregate + combine: h = relu(dis[n]*sum_j dis[s_j]*lin[s_j] + lin[n]*dis^2 + b) [* aei]
template<int NC, bool AEI>
__global__ void k_gcnagg(const float* __restrict__ lin, int stride, int colbase,
                         const int* __restrict__ off, const int* __restrict__ csr,
                         const float* __restrict__ dis, const float* __restrict__ aei,
                         const float* __restrict__ bias, float* __restrict__ h, int n){
  constexpr int TPN = NC/4;
  const int t=threadIdx.x;
  const int node = blockIdx.x*(256/TPN) + t/TPN; if (node>=n) return;
  const int cq = (t%TPN)*4;
  const int j1=off[node+1];
  float4 acc = make_float4(0.f,0.f,0.f,0.f);
  for (int j=off[node]; j<j1; ++j){
    const int s=csr[j];
    const float w=dis[s];
    const float4 v = ld4(lin + (size_t)s*stride + colbase + cq);
    acc.x=fmaf(v.x,w,acc.x); acc.y=fmaf(v.y,w,acc.y);
    acc.z=fmaf(v.z,w,acc.z); acc.w=fmaf(v.w,w,acc.w);
  }
  const float dn=dis[node], d2=dn*dn;
  const float4 own=ld4(lin + (size_t)node*stride + colbase + cq), b4=ld4(bias+cq);
  float4 o;
  o.x=fmaxf(fmaf(acc.x,dn,fmaf(own.x,d2,b4.x)),0.f);
  o.y=fmaxf(fmaf(acc.y,dn,fmaf(own.y,d2,b4.y)),0.f);
  o.z=fmaxf(fmaf(acc.z,dn,fmaf(own.z,d2,b4.z)),0.f);
  o.w=fmaxf(fmaf(acc.w,dn,fmaf(own.w,d2,b4.w)),0.f);
  if (AEI){ const float4 m=ld4(aei+(size_t)node*NC+cq); o.x*=m.x;o.y*=m.y;o.z*=m.z;o.w*=m.w; }
  st4(h + (size_t)node*NC + cq, o);
}

// ---------------------------------------------------------------------------
// Weight transpose + cast: Wt[NP][K] bf16 <- W[K][N] fp32 (rows n>=N zeroed)
// ---------------------------------------------------------------------------
__global__ void k_twt(const float* __restrict__ W, short* __restrict__ Wt,
                      int K, int N, int NP){
  int idx = blockIdx.x*256 + threadIdx.x;
  if (idx >= NP*K) return;
  int n = idx / K, k = idx - n*K;
  Wt[idx] = (n<N)? f2b(W[(size_t)k*N + n]) : (short)0;
}

// ---------------------------------------------------------------------------
// MFMA phase helper (see round-5 notes): per 32-k slab each column needs
// 32 shorts = 4 x float4 (q=0..3).
// ---------------------------------------------------------------------------
template<int KTOT, int NCT>
__device__ __forceinline__ void mm_phase(
    const short* __restrict__ Wt,
    short (*As)[264], short (*Bs)[40],
    int t, int lane, int arow, int kgrp, f32x4* acc)
{
  constexpr int KS = KTOT/32;
  constexpr int NC = NCT*16;
  #pragma unroll
  for (int kb=0; kb<KS; ++kb){
    for (int i=t; i<NC*4; i+=256){
      int col = i>>2, q = i&3;
      const float4 w = *(const float4*)(Wt + (size_t)col*KTOT + kb*32 + q*8);
      *(float4*)&Bs[col][q*8] = w;
    }
    __syncthreads();
    const bf16x8 a = *(const bf16x8*)&As[arow][kb*32 + kgrp*8];
    #pragma unroll
    for (int ct=0; ct<NCT; ++ct){
      const bf16x8 b = *(const bf16x8*)&Bs[ct*16 + (lane&15)][kgrp*8];
      acc[ct] = __builtin_amdgcn_mfma_f32_16x16x32_bf16(a, b, acc[ct], 0, 0, 0);
    }
    __syncthreads();
  }
}

// ---------------------------------------------------------------------------
// Fused edge mega-kernel (bf16 MFMA): gate+emlp1+emlp2+elin1+elin2 -> elog
// ---------------------------------------------------------------------------
__global__ __launch_bounds__(256) void k_edge(
  const float* __restrict__ nf, const float* __restrict__ ni,
  const int* __restrict__ eidx,
  const short* __restrict__ wt_nred, const float* __restrict__ nredb,
  const short* __restrict__ wt_e1,   const float* __restrict__ e1b,
  const short* __restrict__ wt_e2,   const float* __restrict__ e2b,
  const short* __restrict__ wt_l1,   const float* __restrict__ ebng, const float* __restrict__ ebnb,
  const short* __restrict__ wt_l2,
  float* __restrict__ elog)
{
  __shared__ short As[64][264];
  __shared__ short Bs[256][40];
  __shared__ int sidx[64], didx[64];
  const int t = threadIdx.x;
  const int lane = t & 63, wave = t >> 6;
  const int row0 = blockIdx.x * 64;
  const int kgrp = lane >> 4;
  const int arow = wave*16 + (lane & 15);
  const int crow = wave*16 + kgrp*4;

  if (t < 64){ sidx[t]=eidx[2*(row0+t)]; didx[t]=eidx[2*(row0+t)+1]; }
  __syncthreads();

  const int srow = t & 63, seg = t >> 6;

  // ---- phase 1: gate GEMM, A = concat(ni[s], ni[d]) ----
  {
    const float* src = (seg<2)? (ni + (size_t)sidx[srow]*128 + seg*64)
                              : (ni + (size_t)didx[srow]*128 + (seg-2)*64);
    short* dst = &As[srow][seg*64];
    #pragma unroll
    for (int p=0;p<8;p++){
      float4 u = ld4(src + p*8), v = ld4(src + p*8 + 4);
      bf16x8 o;
      o[0]=f2b(u.x);o[1]=f2b(u.y);o[2]=f2b(u.z);o[3]=f2b(u.w);
      o[4]=f2b(v.x);o[5]=f2b(v.y);o[6]=f2b(v.z);o[7]=f2b(v.w);
      *(bf16x8*)(dst + p*8) = o;
    }
  }
  f32x4 acc1[8];
  #pragma unroll
  for (int j=0;j<8;j++) acc1[j] = (f32x4){0.f,0.f,0.f,0.f};
  mm_phase<256,8>(wt_nred, As, Bs, t, lane, arow, kgrp, acc1);

  float g[8][4];
  #pragma unroll
  for (int ct=0;ct<8;ct++){
    const float bb = nredb[ct*16 + (lane&15)];
    #pragma unroll
    for (int r=0;r<4;r++) g[ct][r] = sigm(acc1[ct][r] + bb);
  }

  // ---- phase 2: emlp1 GEMM, A = concat(nf[s], nf[d]-nf[s]) ----
  {
    short* dst = &As[srow][seg*64];
    const int s = sidx[srow], d = didx[srow];
    #pragma unroll
    for (int p=0;p<8;p++){
      float4 u, v;
      if (seg < 2){
        u = ld4(nf + (size_t)s*128 + seg*64 + p*8);
        v = ld4(nf + (size_t)s*128 + seg*64 + p*8 + 4);
      } else {
        float4 ua = ld4(nf + (size_t)d*128 + (seg-2)*64 + p*8);
        float4 ub = ld4(nf + (size_t)s*128 + (seg-2)*64 + p*8);
        float4 va = ld4(nf + (size_t)d*128 + (seg-2)*64 + p*8 + 4);
        float4 vb = ld4(nf + (size_t)s*128 + (seg-2)*64 + p*8 + 4);
        u.x=ua.x-ub.x; u.y=ua.y-ub.y; u.z=ua.z-ub.z; u.w=ua.w-ub.w;
        v.x=va.x-vb.x; v.y=va.y-vb.y; v.z=va.z-vb.z; v.w=va.w-vb.w;
      }
      bf16x8 o;
      o[0]=f2b(u.x);o[1]=f2b(u.y);o[2]=f2b(u.z);o[3]=f2b(u.w);
      o[4]=f2b(v.x);o[5]=f2b(v.y);o[6]=f2b(v.z);o[7]=f2b(v.w);
      *(bf16x8*)(dst + p*8) = o;
    }
  }
  f32x4 acc2[8];
  #pragma unroll
  for (int j=0;j<8;j++) acc2[j] = (f32x4){0.f,0.f,0.f,0.f};
  mm_phase<256,8>(wt_e1, As, Bs, t, lane, arow, kgrp, acc2);

  #pragma unroll
  for (int ct=0;ct<8;ct++){
    const int col = ct*16 + (lane&15);
    const float bb = e1b[col];
    #pragma unroll
    for (int r=0;r<4;r++)
      As[crow+r][col] = f2b(fmaxf(acc2[ct][r] + bb, 0.f) * g[ct][r]);
  }

  // ---- phase 3: emlp2 GEMM (128 -> 256) ----
  f32x4 acc3[16];
  #pragma unroll
  for (int j=0;j<16;j++) acc3[j] = (f32x4){0.f,0.f,0.f,0.f};
  mm_phase<128,16>(wt_e2, As, Bs, t, lane, arow, kgrp, acc3);
  #pragma unroll
  for (int ct=0;ct<16;ct++){
    const int col = ct*16 + (lane&15);
    const float bb = e2b[col];
    #pragma unroll
    for (int r=0;r<4;r++)
      As[crow+r][col] = f2b(fmaxf(acc3[ct][r] + bb, 0.f));
  }

  // ---- phase 4: elin1 + BN + leaky (256 -> 128) ----
  f32x4 acc4[8];
  #pragma unroll
  for (int j=0;j<8;j++) acc4[j] = (f32x4){0.f,0.f,0.f,0.f};
  mm_phase<256,8>(wt_l1, As, Bs, t, lane, arow, kgrp, acc4);
  {
    const float r_ = rsqrtf(1.f + 1e-5f);
    #pragma unroll
    for (int ct=0;ct<8;ct++){
      const int col = ct*16 + (lane&15);
      const float sc = ebng[col]*r_, sh = ebnb[col];
      #pragma unroll
      for (int r=0;r<4;r++){
        float x = fmaf(acc4[ct][r], sc, sh);
        As[crow+r][col] = f2b((x>0.f)? x : 0.2f*x);
      }
    }
  }

  // ---- phase 5: elin2 (128 -> 27, padded 32) ----
  f32x4 acc5[2];
  acc5[0] = (f32x4){0.f,0.f,0.f,0.f}; acc5[1] = (f32x4){0.f,0.f,0.f,0.f};
  mm_phase<128,2>(wt_l2, As, Bs, t, lane, arow, kgrp, acc5);

  float* Lb = (float*)&As[0][0];   // [64][28]
  #pragma unroll
  for (int ct=0;ct<2;ct++){
    const int col = ct*16 + (lane&15);
    if (col < 27){
      #pragma unroll
      for (int r=0;r<4;r++) Lb[(crow+r)*28 + col] = acc5[ct][r];
    }
  }
  __syncthreads();
  for (int i=t; i<64*27; i+=256){
    int rr = i/27, cc = i - rr*27;
    elog[(size_t)(row0+rr)*27 + cc] = Lb[rr*28 + cc];
  }
}

// ---------------------------- tail kernels --------------------------------
__global__ __launch_bounds__(256) void k_softmax_row(float* __restrict__ x, int M){
  const int wave = threadIdx.x>>6, lane = threadIdx.x&63;
  const int r = blockIdx.x*4 + wave; if (r>=M) return;
  float* p = x + (size_t)r*160;
  float v0 = p[lane], v1 = p[64+lane];
  float v2 = (lane<32)? p[128+lane] : -3.4e38f;
  float m = fmaxf(fmaxf(v0,v1),v2);
  for (int o=32;o;o>>=1) m = fmaxf(m, __shfl_xor(m,o));
  float e0=expf(v0-m), e1=expf(v1-m), e2=(lane<32)?expf(v2-m):0.f;
  float s=e0+e1+e2;
  for (int o=32;o;o>>=1) s += __shfl_xor(s,o);
  float inv = 1.f/s;
  p[lane]=e0*inv; p[64+lane]=e1*inv; if(lane<32)p[128+lane]=e2*inv;
}
__global__ void k_colmax(const float* __restrict__ x, uint32* __restrict__ cmax_u, int E){
  __shared__ float red[8][32];
  const int t=threadIdx.x, col=t&31, seg=t>>5;
  float m = -3.4e38f;
  if (col < 27)
    for (int r = blockIdx.x*8 + seg; r < E; r += gridDim.x*8)
      m = fmaxf(m, x[(size_t)r*27+col]);
  red[seg][col]=m; __syncthreads();
  if (t<32){
    float mm=red[0][t];
    #pragma unroll
    for (int s2=1;s2<8;s2++) mm=fmaxf(mm,red[s2][t]);
    if (t<27){
      uint32 u=__float_as_uint(mm);
      u = (u&0x80000000u)? ~u : (u|0x80000000u);
      atomicMax(&cmax_u[t], u);
    }
  }
}
__global__ void k_colfix(const uint32* __restrict__ cmax_u, float* __restrict__ cmaxf){
  int t=threadIdx.x; if (t>=27) return;
  uint32 u=cmax_u[t];
  cmaxf[t] = (u&0x80000000u)? __uint_as_float(u&0x7FFFFFFFu) : __uint_as_float(~u);
}
__global__ void k_colsum(const float* __restrict__ x, const float* __restrict__ cmaxf,
                         float* __restrict__ csum, int E){
  __shared__ float red[8][32];
  const int t=threadIdx.x, col=t&31, seg=t>>5;
  float s = 0.f;
  if (col < 27){
    const float cm = cmaxf[col];
    for (int r = blockIdx.x*8 + seg; r < E; r += gridDim.x*8)
      s += expf(x[(size_t)r*27+col] - cm);
  }
  red[seg][col]=s; __syncthreads();
  if (t<32){
    float ss=red[0][t];
    #pragma unroll
    for (int s2=1;s2<8;s2++) ss+=red[s2][t];
    if (t<27) atomicAdd(&csum[t], ss);
  }
}
__global__ void k_colnorm(float* __restrict__ x, const float* __restrict__ cmaxf,
                          const float* __restrict__ csum, int E){
  int idx=blockIdx.x*256+threadIdx.x;
  if (idx >= E*27) return;
  int c = idx - (idx/27)*27;
  x[idx] = expf(x[idx]-cmaxf[c]) / csum[c];
}

// ---------------------------------------------------------------------------
extern "C" void kernel_launch(void* const* d_in, const int* in_sizes, int n_in,
                              void* d_out, int out_size, void* d_ws, size_t ws_size,
                              hipStream_t stream)
{
  const float* nf     = (const float*)d_in[0];
  const int*   eidx   = (const int*)  d_in[1];
  const float* gcn1W  = (const float*)d_in[2];
  const float* gcn1b  = (const float*)d_in[3];
  const float* gcn2W  = (const float*)d_in[4];
  const float* gcn2b  = (const float*)d_in[5];
  const float* eattnW = (const float*)d_in[6];
  const float* eattnb = (const float*)d_in[7];
  const float* nattnW = (const float*)d_in[8];
  const float* nattnb = (const float*)d_in[9];
  const float* nredW  = (const float*)d_in[10];
  const float* nredb  = (const float*)d_in[11];
  const float* emlp1W = (const float*)d_in[12];
  const float* emlp1b = (const float*)d_in[13];
  const float* emlp2W = (const float*)d_in[14];
  const float* emlp2b = (const float*)d_in[15];
  const float* nlin1W = (const float*)d_in[16];
  const float* nbng   = (const float*)d_in[17];
  const float* nbnb   = (const float*)d_in[18];
  const float* nlin2W = (const float*)d_in[19];
  const float* elin1W = (const float*)d_in[20];
  const float* ebng   = (const float*)d_in[21];
  const float* ebnb   = (const float*)d_in[22];
  const float* elin2W = (const float*)d_in[23];
  (void)in_sizes; (void)n_in; (void)out_size; (void)ws_size;

  const int N = NN, E = EE;
  float* out  = (float*)d_out;
  float* nlog = out;               // N*160
  float* elog = out + (size_t)N*160;       // E*27

  // ---- workspace plan (~237 MB) ----
  float* ws   = (float*)d_ws;
  float* h2   = ws;                        // N*128
  float* lin2 = ws + (size_t)N*128;        // N*128 ; Q at first half, S at second half (dead before lin2)
  float* Q    = lin2;                      // N*64
  float* S    = lin2 + (size_t)N*64;       // N*64
  float* niB  = lin2;                      // after gcnagg2
  float* nx   = lin2;                      // after k_edge
  float* TUL  = ws + (size_t)N*256;        // N*192  [T|U|lin1]
  float* h1   = ws + (size_t)N*448;        // N*64
  float* aei  = ws + (size_t)N*512;        // N*64
  float* dis  = ws + (size_t)N*576;        // N
  float* smalls = ws + (size_t)N*577;      // 96: [0:32) colmax_u, [32:64) colsum, [64:96) cmaxf
  float* Wcat = smalls + 128;              // 128*192 = 24576
  int*   ip   = (int*)(Wcat + 24576);
  int* cntS = ip;                          // N
  int* cntD = ip + N;                      // N
  int* offS = ip + 2*N;                    // N+64
  int* offD = ip + 3*N + 64;               // N+64
  int* curS = ip + 4*N + 128;              // N
  int* curD = ip + 5*N + 128;              // N
  int* csrS = ip + 6*N + 128;              // E
  int* csrD = ip + 6*N + 128 + E;          // E
  int* bsum = ip + 6*N + 128 + 2*E;        // 256
  short* wtb  = (short*)(bsum + 256);
  short* wt_nred = wtb;                    // 128*256
  short* wt_e1   = wtb + 32768;
  short* wt_e2   = wtb + 65536;
  short* wt_l1   = wtb + 98304;
  short* wt_l2   = wtb + 131072;           // 32*128

  const int NB1024 = (N + 1023)/1024;      // 98

  // 0. weight prep (bf16 transposes + Wcat)
  k_twt<<<128,256,0,stream>>>(nredW,  wt_nred, 256, 128, 128);
  k_twt<<<128,256,0,stream>>>(emlp1W, wt_e1,   256, 128, 128);
  k_twt<<<128,256,0,stream>>>(emlp2W, wt_e2,   128, 256, 256);
  k_twt<<<128,256,0,stream>>>(elin1W, wt_l1,   256, 128, 128);
  k_twt<<<16, 256,0,stream>>>(elin2W, wt_l2,   128, 27,  32);
  k_wprep<<<96,256,0,stream>>>(eattnW, gcn1W, Wcat);

  // 1. CSR build (both directions)
  (void)hipMemsetAsync(cntS, 0, 2*(size_t)N*sizeof(int), stream);
  k_hist<<<(E+255)/256,256,0,stream>>>(eidx, cntS, cntD, E);
  k_scan_sum<<<NB1024,256,0,stream>>>(cntS, bsum, N);
  k_scan_top<<<1,256,0,stream>>>(bsum, NB1024);
  k_scan_out<<<NB1024,256,0,stream>>>(cntS, bsum, offS, N);
  k_scan_sum<<<NB1024,256,0,stream>>>(cntD, bsum, N);
  k_scan_top<<<1,256,0,stream>>>(bsum, NB1024);
  k_scan_out<<<NB1024,256,0,stream>>>(cntD, bsum, offD, N);
  k_setend<<<1,64,0,stream>>>(offS, offD, N, E);
  k_copyoff<<<(N+255)/256,256,0,stream>>>(offS, curS, N, E);
  k_copyoff<<<(N+255)/256,256,0,stream>>>(offD, curD, N, E);
  k_fill<<<(E+255)/256,256,0,stream>>>(eidx, curS, curD, csrS, csrD, E);
  k_dis<<<(N+255)/256,256,0,stream>>>(cntD, dis, N);

  // 2. TUL = nf @ [Wbot|Wd|gcn1W]  (one pass over nf)
  gemm_k<128,192,EM_STORE><<<(N+63)/64,256,0,stream>>>(nf, Wcat, nullptr, nullptr, TUL, N);

  // 3. eattn segment means via gathers: Q[n]=sum T[dst] (by src), S[n]=sum U[src] (by dst)
  k_gather<64><<<(N+15)/16,256,0,stream>>>(TUL, 192, 0,  offS, csrS, Q, N);
  k_gather<64><<<(N+15)/16,256,0,stream>>>(TUL, 192, 64, offD, csrD, S, N);
  k_aei3<<<(N*16+255)/256,256,0,stream>>>(TUL, Q, S, cntS, cntD, eattnb, aei, N);

  // 4. GCN conv 1: lin1 already in TUL cols 128..191 -> gather+combine -> h1
  k_gcnagg<64,true><<<(N+15)/16,256,0,stream>>>(TUL, 192, 128, offD, csrD, dis, aei, gcn1b, h1, N);

  // 5. GCN conv 2
  gemm_k<64,128,EM_STORE><<<(N+63)/64,256,0,stream>>>(h1, gcn2W, nullptr, nullptr, lin2, N);
  k_gcnagg<128,false><<<(N+7)/8,256,0,stream>>>(lin2, 128, 0, offD, csrD, dis, nullptr, gcn2b, h2, N);

  // 6. node attention
  gemm_k<128,128,EM_BRELU><<<(N+63)/64,256,0,stream>>>(h2, nattnW, nattnb, nullptr, niB, N);

  // 7. fused edge chain (bf16 MFMA)
  k_edge<<<E/64,256,0,stream>>>(
      nf, niB, eidx,
      wt_nred, nredb, wt_e1, emlp1b, wt_e2, emlp2b,
      wt_l1, ebng, ebnb, wt_l2, elog);

  // 8. node head (nx over niB — niB dead after k_edge)
  gemm_k<128,64,EM_BNLK><<<(N+63)/64,256,0,stream>>>(h2, nlin1W, nbnb, nbng, nx, N);
  gemm_k<64,160,EM_STORE><<<(N+63)/64,256,0,stream>>>(nx, nlin2W, nullptr, nullptr, nlog, N);
  k_softmax_row<<<(N+3)/4,256,0,stream>>>(nlog, N);

  // 9. column softmax over E for edge logits (in place in d_out)
  (void)hipMemsetAsync(smalls, 0, 96*sizeof(float), stream);
  k_colmax<<<1024,256,0,stream>>>(elog, (uint32*)smalls, E);
  k_colfix<<<1,32,0,stream>>>((const uint32*)smalls, smalls+64);
  k_colsum<<<1024,256,0,stream>>>(elog, smalls+64, smalls+32, E);
  k_colnorm<<<(E*27+255)/256,256,0,stream>>>(elog, smalls+64, smalls+32, E);
}

// Round 7
// 911.429 us; speedup vs baseline: 3.8827x; 1.0644x over previous
//
#include <hip/hip_runtime.h>

#define NN 100000
#define EE 320000

typedef unsigned int uint32;
typedef __attribute__((ext_vector_type(8))) short bf16x8;
typedef __attribute__((ext_vector_type(4))) float f32x4;

__device__ __forceinline__ float4 ld4(const float* p){ return *(const float4*)p; }
__device__ __forceinline__ void st4(float* p, const float4 v){ *(float4*)p = v; }
__device__ __forceinline__ float sigm(float x){ return 1.f/(1.f + expf(-x)); }
__device__ __forceinline__ short f2b(float f){
  union { float f; uint32 u; } v; v.f = f;
  uint32 r = (v.u + 0x7FFFu + ((v.u>>16)&1u)) >> 16;   // RNE
  return (short)r;
}

constexpr int EM_STORE=0, EM_BRELU=1, EM_BNLK=2;

// ---------------------------------------------------------------------------
// Generic fp32 tiled GEMM (node path): 64 rows/block, BK=16, 256 threads.
// ---------------------------------------------------------------------------
template<int K,int NOUT,int EM>
__global__ __launch_bounds__(256) void gemm_k(
    const float* __restrict__ A,
    const float* __restrict__ W, const float* __restrict__ bias,
    const float* __restrict__ bng,
    float* __restrict__ C, int M)
{
  constexpr int CN = NOUT/16;
  __shared__ float As[16][68];
  __shared__ float Ws[16][NOUT];
  const int t  = threadIdx.x;
  const int tx = t & 15, ty = t >> 4;
  const int row0 = blockIdx.x * 64;

  float acc[4][CN];
  #pragma unroll
  for (int i=0;i<4;i++)
    #pragma unroll
    for (int j=0;j<CN;j++) acc[i][j]=0.f;

  const int r_st  = t >> 2;
  const int kq_st = (t & 3) * 4;

  for (int k0=0;k0<K;k0+=16) {
    {
      float4 v = make_float4(0.f,0.f,0.f,0.f);
      const int gr = row0 + r_st;
      if (gr < M) v = ld4(A + (size_t)gr*K + k0 + kq_st);
      As[kq_st+0][r_st]=v.x; As[kq_st+1][r_st]=v.y;
      As[kq_st+2][r_st]=v.z; As[kq_st+3][r_st]=v.w;
    }
    {
      constexpr int C4 = NOUT/4;
      for (int i=t;i<16*C4;i+=256){ int kk=i/C4, c4=(i%C4)*4;
        st4(&Ws[kk][c4], ld4(W + (size_t)(k0+kk)*NOUT + c4)); }
    }
    __syncthreads();
    #pragma unroll
    for (int kk=0;kk<16;kk++){
      float a0,a1,a2,a3;
      { const float4 av = *(const float4*)&As[kk][ty*4]; a0=av.x;a1=av.y;a2=av.z;a3=av.w; }
      float b[CN];
      if constexpr ((CN & 3) == 0) {
        #pragma unroll
        for (int j4=0;j4<CN;j4+=4){
          const float4 bv = *(const float4*)&Ws[kk][tx*CN+j4];
          b[j4]=bv.x;b[j4+1]=bv.y;b[j4+2]=bv.z;b[j4+3]=bv.w; }
      } else {
        #pragma unroll
        for (int j=0;j<CN;j++) b[j]=Ws[kk][tx*CN+j];
      }
      #pragma unroll
      for (int j=0;j<CN;j++){
        acc[0][j]=fmaf(a0,b[j],acc[0][j]);
        acc[1][j]=fmaf(a1,b[j],acc[1][j]);
        acc[2][j]=fmaf(a2,b[j],acc[2][j]);
        acc[3][j]=fmaf(a3,b[j],acc[3][j]);
      }
    }
    __syncthreads();
  }

  float sc[CN], sh[CN];
  if constexpr (EM==EM_BNLK) {
    const float r_ = rsqrtf(1.f + 1e-5f);
    #pragma unroll
    for (int j=0;j<CN;j++){ int c=tx*CN+j; sc[j]=bng[c]*r_; sh[j]=bias[c]; }
  }
  #pragma unroll
  for (int i=0;i<4;i++){
    const int r  = row0 + ty*4+i;
    if (r >= M) continue;
    #pragma unroll
    for (int j=0;j<CN;j++){
      const int c = tx*CN+j;
      float v = acc[i][j];
      if constexpr (EM==EM_BRELU) v = fmaxf(v + bias[c], 0.f);
      else if constexpr (EM==EM_BNLK){ float x = fmaf(v, sc[j], sh[j]); v = (x>0.f)? x : 0.2f*x; }
      C[(size_t)r*NOUT + c] = v;
    }
  }
}

// ---------------------------------------------------------------------------
// CSR build: histogram -> scan -> fill
// ---------------------------------------------------------------------------
__global__ void k_hist(const int* __restrict__ eidx, int* cntS, int* cntD, int E){
  int e = blockIdx.x*256+threadIdx.x; if (e>=E) return;
  atomicAdd(&cntS[eidx[2*e]], 1);
  atomicAdd(&cntD[eidx[2*e+1]], 1);
}
__global__ void k_scan_sum(const int* __restrict__ cnt, int* bsum, int n){
  __shared__ int red[256];
  const int b=blockIdx.x, t=threadIdx.x;
  int s=0;
  for (int i=b*1024+t; i<n && i<(b+1)*1024; i+=256) s += cnt[i];
  red[t]=s; __syncthreads();
  for (int o=128;o;o>>=1){ if(t<o) red[t]+=red[t+o]; __syncthreads(); }
  if (t==0) bsum[b]=red[0];
}
__global__ void k_scan_top(int* bsum, int nb){   // 1 block, nb<=256
  __shared__ int sh[256];
  const int t=threadIdx.x;
  int v=(t<nb)?bsum[t]:0;
  sh[t]=v; __syncthreads();
  for (int o=1;o<256;o<<=1){
    int u=0; if(t>=o) u=sh[t-o];
    __syncthreads();
    sh[t]+=u;
    __syncthreads();
  }
  if (t<nb) bsum[t]=sh[t]-v;   // exclusive
}
__global__ void k_scan_out(const int* __restrict__ cnt, const int* __restrict__ bofs,
                           int* __restrict__ off, int n){
  __shared__ int sh[256];
  const int b=blockIdx.x, t=threadIdx.x;
  const int base=b*1024+t*4;
  int c0=0,c1=0,c2=0,c3=0;
  if(base+0<n)c0=cnt[base+0];
  if(base+1<n)c1=cnt[base+1];
  if(base+2<n)c2=cnt[base+2];
  if(base+3<n)c3=cnt[base+3];
  int s=c0+c1+c2+c3;
  sh[t]=s; __syncthreads();
  int v=s;
  for (int o=1;o<256;o<<=1){
    int u=0; if(t>=o) u=sh[t-o];
    __syncthreads();
    sh[t]+=u;
    __syncthreads();
  }
  const int tofs = sh[t]-v + bofs[b];
  if(base+0<n) off[base+0]=tofs;
  if(base+1<n) off[base+1]=tofs+c0;
  if(base+2<n) off[base+2]=tofs+c0+c1;
  if(base+3<n) off[base+3]=tofs+c0+c1+c2;
}
__global__ void k_copyoff(const int* __restrict__ off, int* __restrict__ cur, int n, int E){
  int i=blockIdx.x*256+threadIdx.x;
  if (i<n) cur[i]=off[i];
}
__global__ void k_setend(int* offS, int* offD, int n, int E){
  if (threadIdx.x==0 && blockIdx.x==0){ offS[n]=E; offD[n]=E; }
}
__global__ void k_fill(const int* __restrict__ eidx, int* curS, int* curD,
                       int* __restrict__ csrS, int* __restrict__ csrD, int E){
  int e=blockIdx.x*256+threadIdx.x; if (e>=E) return;
  const int s=eidx[2*e], d=eidx[2*e+1];
  csrS[atomicAdd(&curS[s],1)] = d;
  csrD[atomicAdd(&curD[d],1)] = s;
}
__global__ void k_dis(const int* __restrict__ cntD, float* __restrict__ dis, int n){
  int i=blockIdx.x*256+threadIdx.x; if(i>=n)return;
  dis[i]=rsqrtf((float)cntD[i]+1.f);
}

// ---------------------------------------------------------------------------
// Wcat = [Wbot | Wd | gcn1W]  (128 x 192 fp32)
// ---------------------------------------------------------------------------
__global__ void k_wprep(const float* __restrict__ eattnW, const float* __restrict__ gcn1W,
                        float* __restrict__ Wcat){
  int idx=blockIdx.x*256+threadIdx.x; if (idx>=128*192) return;
  int k=idx/192, c=idx-k*192;
  float v;
  if (c<64)       v = eattnW[(size_t)(128+k)*64 + c];
  else if (c<128) v = eattnW[(size_t)k*64 + (c-64)] - eattnW[(size_t)(128+k)*64 + (c-64)];
  else            v = gcn1W[(size_t)k*64 + (c-128)];
  Wcat[idx]=v;
}

// ---------------------------------------------------------------------------
// CSR gather-sum
// ---------------------------------------------------------------------------
template<int NC>
__global__ void k_gather(const float* __restrict__ src, int stride, int colbase,
                         const int* __restrict__ off, const int* __restrict__ csr,
                         float* __restrict__ out, int n){
  constexpr int TPN = NC/4;
  const int t=threadIdx.x;
  const int node = blockIdx.x*(256/TPN) + t/TPN; if (node>=n) return;
  const int cq = (t%TPN)*4;
  const int j1=off[node+1];
  float4 acc = make_float4(0.f,0.f,0.f,0.f);
  for (int j=off[node]; j<j1; ++j){
    const float4 v = ld4(src + (size_t)csr[j]*stride + colbase + cq);
    acc.x+=v.x; acc.y+=v.y; acc.z+=v.z; acc.w+=v.w;
  }
  st4(out + (size_t)node*NC + cq, acc);
}

// aei = sigmoid(row*col)
__global__ void k_aei3(const float* __restrict__ TUL, const float* __restrict__ Q,
                       const float* __restrict__ S, const int* __restrict__ cntS,
                       const int* __restrict__ cntD, const float* __restrict__ bias,
                       float* __restrict__ aei, int n){
  int idx=blockIdx.x*256+threadIdx.x; if (idx>=n*16) return;
  const int i=idx>>4, cq=(idx&15)*4;
  const float cS=(float)cntS[i], cD=(float)cntD[i];
  const float iS=1.f/fmaxf(cS,1.f), iD=1.f/fmaxf(cD,1.f);
  const float* tul = TUL + (size_t)i*192;
  const float4 T4=ld4(tul+cq), U4=ld4(tul+64+cq);
  const float4 Q4=ld4(Q+(size_t)i*64+cq), S4=ld4(S+(size_t)i*64+cq), b4=ld4(bias+cq);
  float4 o;
  o.x=sigm(((cS*(U4.x+b4.x)+Q4.x)*iS) * ((cD*(T4.x+b4.x)+S4.x)*iD));
  o.y=sigm(((cS*(U4.y+b4.y)+Q4.y)*iS) * ((cD*(T4.y+b4.y)+S4.y)*iD));
  o.z=sigm(((cS*(U4.z+b4.z)+Q4.z)*iS) * ((cD*(T4.z+b4.z)+S4.z)*iD));
  o.w=sigm(((cS*(U4.w+b4.w)+Q4.w)*iS) * ((cD*(T4.w+b4.w)+S4.w)*iD));
  st4(aei + (size_t)i*64 + cq, o);
}

// GCN aggregate + combine
template<int NC, bool AEI>
__global__ void k_gcnagg(const float* __restrict__ lin, int stride, int colbase,
                         const int* __restrict__ off, const int* __restrict__ csr,
                         const float* __restrict__ dis, const float* __restrict__ aei,
                         const float* __restrict__ bias, float* __restrict__ h, int n){
  constexpr int TPN = NC/4;
  const int t=threadIdx.x;
  const int node = blockIdx.x*(256/TPN) + t/TPN; if (node>=n) return;
  const int cq = (t%TPN)*4;
  const int j1=off[node+1];
  float4 acc = make_float4(0.f,0.f,0.f,0.f);
  for (int j=off[node]; j<j1; ++j){
    const int s=csr[j];
    const float w=dis[s];
    const float4 v = ld4(lin + (size_t)s*stride + colbase + cq);
    acc.x=fmaf(v.x,w,acc.x); acc.y=fmaf(v.y,w,acc.y);
    acc.z=fmaf(v.z,w,acc.z); acc.w=fmaf(v.w,w,acc.w);
  }
  const float dn=dis[node], d2=dn*dn;
  const float4 own=ld4(lin + (size_t)node*stride + colbase + cq), b4=ld4(bias+cq);
  float4 o;
  o.x=fmaxf(fmaf(acc.x,dn,fmaf(own.x,d2,b4.x)),0.f);
  o.y=fmaxf(fmaf(acc.y,dn,fmaf(own.y,d2,b4.y)),0.f);
  o.z=fmaxf(fmaf(acc.z,dn,fmaf(own.z,d2,b4.z)),0.f);
  o.w=fmaxf(fmaf(acc.w,dn,fmaf(own.w,d2,b4.w)),0.f);
  if (AEI){ const float4 m=ld4(aei+(size_t)node*NC+cq); o.x*=m.x;o.y*=m.y;o.z*=m.z;o.w*=m.w; }
  st4(h + (size_t)node*NC + cq, o);
}

// ---------------------------------------------------------------------------
// Weight transpose + cast: Wt[NP][K] bf16 <- W[K][N] fp32
// ---------------------------------------------------------------------------
__global__ void k_twt(const float* __restrict__ W, short* __restrict__ Wt,
                      int K, int N, int NP){
  int idx = blockIdx.x*256 + threadIdx.x;
  if (idx >= NP*K) return;
  int n = idx / K, k = idx - n*K;
  Wt[idx] = (n<N)? f2b(W[(size_t)k*N + n]) : (short)0;
}

// ---------------------------------------------------------------------------
// Double-buffered MFMA phase (512 threads, 2 tiles/block):
// C(128 x NCT*16) += As(128 x KTOT bf16) @ Wt^T.  NCT <= 8.
// One sync per 32-k slab; next slab's weights prefetched to regs during MFMA.
// ---------------------------------------------------------------------------
template<int KTOT, int NCT>
__device__ __forceinline__ void mm_phase(
    const short* __restrict__ Wt,
    short (*As)[264], short (*Bs)[128][40],
    int t, int lane, int arow, int kgrp, f32x4* acc)
{
  constexpr int KS = KTOT/32;
  constexpr int NC = NCT*16;          // 128 or 32
  const bool act = (t < NC*4);
  const int col = t>>2, q = t&3;
  const short* wp = Wt + (size_t)col*KTOT + q*8;
  float4 r;
  if (act){
    r = *(const float4*)wp;
    *(float4*)&Bs[0][col][q*8] = r;
  }
  __syncthreads();
  #pragma unroll
  for (int kb=0; kb<KS; ++kb){
    if (act && kb+1<KS) r = *(const float4*)(wp + (kb+1)*32);
    const bf16x8 a = *(const bf16x8*)&As[arow][kb*32 + kgrp*8];
    #pragma unroll
    for (int ct=0; ct<NCT; ++ct){
      const bf16x8 b = *(const bf16x8*)&Bs[kb&1][ct*16 + (lane&15)][kgrp*8];
      acc[ct] = __builtin_amdgcn_mfma_f32_16x16x32_bf16(a, b, acc[ct], 0, 0, 0);
    }
    if (act && kb+1<KS) *(float4*)&Bs[(kb+1)&1][col][q*8] = r;
    __syncthreads();
  }
}

// ---------------------------------------------------------------------------
// Fused edge mega-kernel (bf16 MFMA, 512 thr, 128 edges/block):
//   gate + emlp1(*G) + emlp2 + elin1(BN,leaky) + elin2 -> elog
// ---------------------------------------------------------------------------
__global__ __launch_bounds__(512) void k_edge(
  const float* __restrict__ nf, const float* __restrict__ ni,
  const int* __restrict__ eidx,
  const short* __restrict__ wt_nred, const float* __restrict__ nredb,
  const short* __restrict__ wt_e1,   const float* __restrict__ e1b,
  const short* __restrict__ wt_e2,   const float* __restrict__ e2b,
  const short* __restrict__ wt_l1,   const float* __restrict__ ebng, const float* __restrict__ ebnb,
  const short* __restrict__ wt_l2,
  float* __restrict__ elog)
{
  __shared__ short As[128][264];     // 67584 B
  __shared__ short Bs[2][128][40];   // 20480 B
  __shared__ int sidx[128], didx[128];
  const int t = threadIdx.x;
  const int lane = t & 63, wave = t >> 6;
  const int tile = wave >> 2, wv = wave & 3;
  const int row0 = blockIdx.x * 128;
  const int kgrp = lane >> 4;
  const int arow = tile*64 + wv*16 + (lane & 15);
  const int crow = tile*64 + wv*16 + kgrp*4;

  if (t < 128){ sidx[t]=eidx[2*(row0+t)]; didx[t]=eidx[2*(row0+t)+1]; }
  __syncthreads();

  const int srow = t >> 2, seg = t & 3;   // staging: 64 floats of one row each

  // ---- phase 1: gate GEMM, A = concat(ni[s], ni[d]) ----
  {
    const float* src = (seg<2)? (ni + (size_t)sidx[srow]*128 + seg*64)
                              : (ni + (size_t)didx[srow]*128 + (seg-2)*64);
    short* dst = &As[srow][seg*64];
    #pragma unroll
    for (int p=0;p<8;p++){
      float4 u = ld4(src + p*8), v = ld4(src + p*8 + 4);
      bf16x8 o;
      o[0]=f2b(u.x);o[1]=f2b(u.y);o[2]=f2b(u.z);o[3]=f2b(u.w);
      o[4]=f2b(v.x);o[5]=f2b(v.y);o[6]=f2b(v.z);o[7]=f2b(v.w);
      *(bf16x8*)(dst + p*8) = o;
    }
  }
  f32x4 acc1[8];
  #pragma unroll
  for (int j=0;j<8;j++) acc1[j] = (f32x4){0.f,0.f,0.f,0.f};
  mm_phase<256,8>(wt_nred, As, Bs, t, lane, arow, kgrp, acc1);

  float g[8][4];
  #pragma unroll
  for (int ct=0;ct<8;ct++){
    const float bb = nredb[ct*16 + (lane&15)];
    #pragma unroll
    for (int r=0;r<4;r++) g[ct][r] = sigm(acc1[ct][r] + bb);
  }

  // ---- phase 2: emlp1 GEMM, A = concat(nf[s], nf[d]-nf[s]) ----
  {
    short* dst = &As[srow][seg*64];
    const int s = sidx[srow], d = didx[srow];
    #pragma unroll
    for (int p=0;p<8;p++){
      float4 u, v;
      if (seg < 2){
        u = ld4(nf + (size_t)s*128 + seg*64 + p*8);
        v = ld4(nf + (size_t)s*128 + seg*64 + p*8 + 4);
      } else {
        float4 ua = ld4(nf + (size_t)d*128 + (seg-2)*64 + p*8);
        float4 ub = ld4(nf + (size_t)s*128 + (seg-2)*64 + p*8);
        float4 va = ld4(nf + (size_t)d*128 + (seg-2)*64 + p*8 + 4);
        float4 vb = ld4(nf + (size_t)s*128 + (seg-2)*64 + p*8 + 4);
        u.x=ua.x-ub.x; u.y=ua.y-ub.y; u.z=ua.z-ub.z; u.w=ua.w-ub.w;
        v.x=va.x-vb.x; v.y=va.y-vb.y; v.z=va.z-vb.z; v.w=va.w-vb.w;
      }
      bf16x8 o;
      o[0]=f2b(u.x);o[1]=f2b(u.y);o[2]=f2b(u.z);o[3]=f2b(u.w);
      o[4]=f2b(v.x);o[5]=f2b(v.y);o[6]=f2b(v.z);o[7]=f2b(v.w);
      *(bf16x8*)(dst + p*8) = o;
    }
  }
  f32x4 acc2[8];
  #pragma unroll
  for (int j=0;j<8;j++) acc2[j] = (f32x4){0.f,0.f,0.f,0.f};
  mm_phase<256,8>(wt_e1, As, Bs, t, lane, arow, kgrp, acc2);

  // ef1 = relu(acc2+b)*G -> As
  #pragma unroll
  for (int ct=0;ct<8;ct++){
    const int col = ct*16 + (lane&15);
    const float bb = e1b[col];
    #pragma unroll
    for (int r=0;r<4;r++)
      As[crow+r][col] = f2b(fmaxf(acc2[ct][r] + bb, 0.f) * g[ct][r]);
  }

  // ---- phase 3: emlp2 GEMM (128 -> 256), two 128-col halves ----
  f32x4 acc3[16];
  #pragma unroll
  for (int j=0;j<16;j++) acc3[j] = (f32x4){0.f,0.f,0.f,0.f};
  mm_phase<128,8>(wt_e2,                    As, Bs, t, lane, arow, kgrp, acc3);
  mm_phase<128,8>(wt_e2 + (size_t)128*128,  As, Bs, t, lane, arow, kgrp, acc3+8);
  #pragma unroll
  for (int ct=0;ct<16;ct++){
    const int col = ct*16 + (lane&15);
    const float bb = e2b[col];
    #pragma unroll
    for (int r=0;r<4;r++)
      As[crow+r][col] = f2b(fmaxf(acc3[ct][r] + bb, 0.f));
  }

  // ---- phase 4: elin1 + BN + leaky (256 -> 128) ----
  f32x4 acc4[8];
  #pragma unroll
  for (int j=0;j<8;j++) acc4[j] = (f32x4){0.f,0.f,0.f,0.f};
  mm_phase<256,8>(wt_l1, As, Bs, t, lane, arow, kgrp, acc4);
  {
    const float r_ = rsqrtf(1.f + 1e-5f);
    #pragma unroll
    for (int ct=0;ct<8;ct++){
      const int col = ct*16 + (lane&15);
      const float sc = ebng[col]*r_, sh = ebnb[col];
      #pragma unroll
      for (int r=0;r<4;r++){
        float x = fmaf(acc4[ct][r], sc, sh);
        As[crow+r][col] = f2b((x>0.f)? x : 0.2f*x);
      }
    }
  }

  // ---- phase 5: elin2 (128 -> 27, padded 32) ----
  f32x4 acc5[2];
  acc5[0] = (f32x4){0.f,0.f,0.f,0.f}; acc5[1] = (f32x4){0.f,0.f,0.f,0.f};
  mm_phase<128,2>(wt_l2, As, Bs, t, lane, arow, kgrp, acc5);

  // bounce through LDS for coalesced fp32 store
  float* Lb = (float*)&As[0][0];   // [128][28] fp32 = 14336 B
  #pragma unroll
  for (int ct=0;ct<2;ct++){
    const int col = ct*16 + (lane&15);
    if (col < 27){
      #pragma unroll
      for (int r=0;r<4;r++) Lb[(crow+r)*28 + col] = acc5[ct][r];
    }
  }
  __syncthreads();
  for (int i=t; i<128*27; i+=512){
    int rr = i/27, cc = i - rr*27;
    elog[(size_t)(row0+rr)*27 + cc] = Lb[rr*28 + cc];
  }
}

// ---------------------------- tail kernels --------------------------------
__global__ __launch_bounds__(256) void k_softmax_row(float* __restrict__ x, int M){
  const int wave = threadIdx.x>>6, lane = threadIdx.x&63;
  const int r = blockIdx.x*4 + wave; if (r>=M) return;
  float* p = x + (size_t)r*160;
  float v0 = p[lane], v1 = p[64+lane];
  float v2 = (lane<32)? p[128+lane] : -3.4e38f;
  float m = fmaxf(fmaxf(v0,v1),v2);
  for (int o=32;o;o>>=1) m = fmaxf(m, __shfl_xor(m,o));
  float e0=expf(v0-m), e1=expf(v1-m), e2=(lane<32)?expf(v2-m):0.f;
  float s=e0+e1+e2;
  for (int o=32;o;o>>=1) s += __shfl_xor(s,o);
  float inv = 1.f/s;
  p[lane]=e0*inv; p[64+lane]=e1*inv; if(lane<32)p[128+lane]=e2*inv;
}
__global__ void k_colmax(const float* __restrict__ x, uint32* __restrict__ cmax_u, int E){
  __shared__ float red[8][32];
  const int t=threadIdx.x, col=t&31, seg=t>>5;
  float m = -3.4e38f;
  if (col < 27)
    for (int r = blockIdx.x*8 + seg; r < E; r += gridDim.x*8)
      m = fmaxf(m, x[(size_t)r*27+col]);
  red[seg][col]=m; __syncthreads();
  if (t<32){
    float mm=red[0][t];
    #pragma unroll
    for (int s2=1;s2<8;s2++) mm=fmaxf(mm,red[s2][t]);
    if (t<27){
      uint32 u=__float_as_uint(mm);
      u = (u&0x80000000u)? ~u : (u|0x80000000u);
      atomicMax(&cmax_u[t], u);
    }
  }
}
__global__ void k_colfix(const uint32* __restrict__ cmax_u, float* __restrict__ cmaxf){
  int t=threadIdx.x; if (t>=27) return;
  uint32 u=cmax_u[t];
  cmaxf[t] = (u&0x80000000u)? __uint_as_float(u&0x7FFFFFFFu) : __uint_as_float(~u);
}
__global__ void k_colsum(const float* __restrict__ x, const float* __restrict__ cmaxf,
                         float* __restrict__ csum, int E){
  __shared__ float red[8][32];
  const int t=threadIdx.x, col=t&31, seg=t>>5;
  float s = 0.f;
  if (col < 27){
    const float cm = cmaxf[col];
    for (int r = blockIdx.x*8 + seg; r < E; r += gridDim.x*8)
      s += expf(x[(size_t)r*27+col] - cm);
  }
  red[seg][col]=s; __syncthreads();
  if (t<32){
    float ss=red[0][t];
    #pragma unroll
    for (int s2=1;s2<8;s2++) ss+=red[s2][t];
    if (t<27) atomicAdd(&csum[t], ss);
  }
}
__global__ void k_colnorm(float* __restrict__ x, const float* __restrict__ cmaxf,
                          const float* __restrict__ csum, int E){
  int idx=blockIdx.x*256+threadIdx.x;
  if (idx >= E*27) return;
  int c = idx - (idx/27)*27;
  x[idx] = expf(x[idx]-cmaxf[c]) / csum[c];
}

// ---------------------------------------------------------------------------
extern "C" void kernel_launch(void* const* d_in, const int* in_sizes, int n_in,
                              void* d_out, int out_size, void* d_ws, size_t ws_size,
                              hipStream_t stream)
{
  const float* nf     = (const float*)d_in[0];
  const int*   eidx   = (const int*)  d_in[1];
  const float* gcn1W  = (const float*)d_in[2];
  const float* gcn1b  = (const float*)d_in[3];
  const float* gcn2W  = (const float*)d_in[4];
  const float* gcn2b  = (const float*)d_in[5];
  const float* eattnW = (const float*)d_in[6];
  const float* eattnb = (const float*)d_in[7];
  const float* nattnW = (const float*)d_in[8];
  const float* nattnb = (const float*)d_in[9];
  const float* nredW  = (const float*)d_in[10];
  const float* nredb  = (const float*)d_in[11];
  const float* emlp1W = (const float*)d_in[12];
  const float* emlp1b = (const float*)d_in[13];
  const float* emlp2W = (const float*)d_in[14];
  const float* emlp2b = (const float*)d_in[15];
  const float* nlin1W = (const float*)d_in[16];
  const float* nbng   = (const float*)d_in[17];
  const float* nbnb   = (const float*)d_in[18];
  const float* nlin2W = (const float*)d_in[19];
  const float* elin1W = (const float*)d_in[20];
  const float* ebng   = (const float*)d_in[21];
  const float* ebnb   = (const float*)d_in[22];
  const float* elin2W = (const float*)d_in[23];
  (void)in_sizes; (void)n_in; (void)out_size; (void)ws_size;

  const int N = NN, E = EE;
  float* out  = (float*)d_out;
  float* nlog = out;                       // N*160
  float* elog = out + (size_t)N*160;       // E*27

  // ---- workspace plan (~237 MB) ----
  float* ws   = (float*)d_ws;
  float* h2   = ws;                        // N*128
  float* lin2 = ws + (size_t)N*128;        // N*128 ; Q/S early, niB/nx later
  float* Q    = lin2;                      // N*64
  float* S    = lin2 + (size_t)N*64;       // N*64
  float* niB  = lin2;
  float* nx   = lin2;
  float* TUL  = ws + (size_t)N*256;        // N*192  [T|U|lin1]
  float* h1   = ws + (size_t)N*448;        // N*64
  float* aei  = ws + (size_t)N*512;        // N*64
  float* dis  = ws + (size_t)N*576;        // N
  float* smalls = ws + (size_t)N*577;      // 96
  float* Wcat = smalls + 128;              // 128*192
  int*   ip   = (int*)(Wcat + 24576);
  int* cntS = ip;                          // N
  int* cntD = ip + N;                      // N
  int* offS = ip + 2*N;                    // N+64
  int* offD = ip + 3*N + 64;               // N+64
  int* curS = ip + 4*N + 128;              // N
  int* curD = ip + 5*N + 128;              // N
  int* csrS = ip + 6*N + 128;              // E
  int* csrD = ip + 6*N + 128 + E;          // E
  int* bsum = ip + 6*N + 128 + 2*E;        // 256
  short* wtb  = (short*)(bsum + 256);
  short* wt_nred = wtb;                    // 128*256
  short* wt_e1   = wtb + 32768;
  short* wt_e2   = wtb + 65536;
  short* wt_l1   = wtb + 98304;
  short* wt_l2   = wtb + 131072;           // 32*128

  const int NB1024 = (N + 1023)/1024;      // 98

  // 0. weight prep
  k_twt<<<128,256,0,stream>>>(nredW,  wt_nred, 256, 128, 128);
  k_twt<<<128,256,0,stream>>>(emlp1W, wt_e1,   256, 128, 128);
  k_twt<<<128,256,0,stream>>>(emlp2W, wt_e2,   128, 256, 256);
  k_twt<<<128,256,0,stream>>>(elin1W, wt_l1,   256, 128, 128);
  k_twt<<<16, 256,0,stream>>>(elin2W, wt_l2,   128, 27,  32);
  k_wprep<<<96,256,0,stream>>>(eattnW, gcn1W, Wcat);

  // 1. CSR build (both directions)
  (void)hipMemsetAsync(cntS, 0, 2*(size_t)N*sizeof(int), stream);
  k_hist<<<(E+255)/256,256,0,stream>>>(eidx, cntS, cntD, E);
  k_scan_sum<<<NB1024,256,0,stream>>>(cntS, bsum, N);
  k_scan_top<<<1,256,0,stream>>>(bsum, NB1024);
  k_scan_out<<<NB1024,256,0,stream>>>(cntS, bsum, offS, N);
  k_scan_sum<<<NB1024,256,0,stream>>>(cntD, bsum, N);
  k_scan_top<<<1,256,0,stream>>>(bsum, NB1024);
  k_scan_out<<<NB1024,256,0,stream>>>(cntD, bsum, offD, N);
  k_setend<<<1,64,0,stream>>>(offS, offD, N, E);
  k_copyoff<<<(N+255)/256,256,0,stream>>>(offS, curS, N, E);
  k_copyoff<<<(N+255)/256,256,0,stream>>>(offD, curD, N, E);
  k_fill<<<(E+255)/256,256,0,stream>>>(eidx, curS, curD, csrS, csrD, E);
  k_dis<<<(N+255)/256,256,0,stream>>>(cntD, dis, N);

  // 2. TUL = nf @ [Wbot|Wd|gcn1W]
  gemm_k<128,192,EM_STORE><<<(N+63)/64,256,0,stream>>>(nf, Wcat, nullptr, nullptr, TUL, N);

  // 3. eattn segment means via gathers
  k_gather<64><<<(N+15)/16,256,0,stream>>>(TUL, 192, 0,  offS, csrS, Q, N);
  k_gather<64><<<(N+15)/16,256,0,stream>>>(TUL, 192, 64, offD, csrD, S, N);
  k_aei3<<<(N*16+255)/256,256,0,stream>>>(TUL, Q, S, cntS, cntD, eattnb, aei, N);

  // 4. GCN conv 1
  k_gcnagg<64,true><<<(N+15)/16,256,0,stream>>>(TUL, 192, 128, offD, csrD, dis, aei, gcn1b, h1, N);

  // 5. GCN conv 2
  gemm_k<64,128,EM_STORE><<<(N+63)/64,256,0,stream>>>(h1, gcn2W, nullptr, nullptr, lin2, N);
  k_gcnagg<128,false><<<(N+7)/8,256,0,stream>>>(lin2, 128, 0, offD, csrD, dis, nullptr, gcn2b, h2, N);

  // 6. node attention
  gemm_k<128,128,EM_BRELU><<<(N+63)/64,256,0,stream>>>(h2, nattnW, nattnb, nullptr, niB, N);

  // 7. fused edge chain (bf16 MFMA, 2 tiles/block, double-buffered)
  k_edge<<<E/128,512,0,stream>>>(
      nf, niB, eidx,
      wt_nred, nredb, wt_e1, emlp1b, wt_e2, emlp2b,
      wt_l1, ebng, ebnb, wt_l2, elog);

  // 8. node head
  gemm_k<128,64,EM_BNLK><<<(N+63)/64,256,0,stream>>>(h2, nlin1W, nbnb, nbng, nx, N);
  gemm_k<64,160,EM_STORE><<<(N+63)/64,256,0,stream>>>(nx, nlin2W, nullptr, nullptr, nlog, N);
  k_softmax_row<<<(N+3)/4,256,0,stream>>>(nlog, N);

  // 9. column softmax over E (in place in d_out)
  (void)hipMemsetAsync(smalls, 0, 96*sizeof(float), stream);
  k_colmax<<<1024,256,0,stream>>>(elog, (uint32*)smalls, E);
  k_colfix<<<1,32,0,stream>>>((const uint32*)smalls, smalls+64);
  k_colsum<<<1024,256,0,stream>>>(elog, smalls+64, smalls+32, E);
  k_colnorm<<<(E*27+255)/256,256,0,stream>>>(elog, smalls+64, smalls+32, E);
}